// Round 13
// baseline (359.018 us; speedup 1.0000x reference)
//
#include <hip/hip_runtime.h>

// EncoderBlock: B=2, S=2048, D=1024, H=16, HD=64, F=4096, M=B*S=4096 tokens.

typedef unsigned short u16;
typedef unsigned int u32;
typedef __attribute__((ext_vector_type(8))) __bf16 bf16x8;
typedef __attribute__((ext_vector_type(4))) float f32x4;
typedef __attribute__((ext_vector_type(4))) short s16x4;
typedef __attribute__((ext_vector_type(2))) u32 u32x2;

__device__ __forceinline__ u16 f2bf(float f) {
  u32 u = __float_as_uint(f);
  u += 0x7fffu + ((u >> 16) & 1u);   // RNE
  return (u16)(u >> 16);
}

__device__ __forceinline__ float bf2f(u16 h) {
  return __uint_as_float((u32)h << 16);
}

__device__ __forceinline__ u32 pk_bf_trunc(float a, float b) {
  return (__float_as_uint(a) >> 16) | (__float_as_uint(b) & 0xffff0000u);
}

// Schraudolph-style exp2: 2 full-rate VALU ops vs quarter-rate v_exp_f32.
__device__ __forceinline__ float exp2_fast(float x) {
  float t = __builtin_fmaf(x, 8388608.0f, 1064992506.0f);
  return __int_as_float((int)t);
}

__device__ __forceinline__ void async16(const void* g, void* l) {
  __builtin_amdgcn_global_load_lds((__attribute__((address_space(1))) void*)g,
                                   (__attribute__((address_space(3))) void*)l,
                                   16, 0, 0);
}

__device__ __forceinline__ f32x4 mfma16(bf16x8 a, bf16x8 b, f32x4 c) {
  return __builtin_amdgcn_mfma_f32_16x16x32_bf16(a, b, c, 0, 0, 0);
}

__device__ __forceinline__ f32x4 mfma_pv(s16x4 a, s16x4 b, f32x4 c) {
#if __has_builtin(__builtin_amdgcn_mfma_f32_16x16x16bf16_1k)
  return __builtin_amdgcn_mfma_f32_16x16x16bf16_1k(a, b, c, 0, 0, 0);
#else
  f32x4 d;
  asm("v_mfma_f32_16x16x16_bf16 %0, %1, %2, %3" : "=v"(d) : "v"(a), "v"(b), "v"(c));
  return d;
#endif
}

// ------- fused fp32 -> bf16 convert for all 5 tensors (1 launch) -------
// regions (1024-elem blocks): qkv_w 3072 | out_w 1024 | f1 4096 | f2 4096 | src 4096
// qkv_w rows are PERMUTED on write into grouped order [q 1024 | k 1024 | v 1024].
__global__ __launch_bounds__(256)
void cvt_all(const float* __restrict__ qkv_w, const float* __restrict__ out_w,
             const float* __restrict__ f1, const float* __restrict__ f2,
             const float* __restrict__ src,
             u16* __restrict__ o_qkv, u16* __restrict__ o_out,
             u16* __restrict__ o_f1, u16* __restrict__ o_f2,
             u16* __restrict__ o_src) {
  int b = blockIdx.x;
  const float* in;
  u16* out;
  int lb, ob;
  if (b < 3072) {
    int h = b / 192, c = b - h * 192;
    ob = (c < 64) ? h * 64 + c : (c < 128) ? 1024 + h * 64 + (c - 64)
                                           : 2048 + h * 64 + (c - 128);
    in = qkv_w; out = o_qkv; lb = b;
  }
  else if (b < 4096)  { in = out_w; out = o_out; lb = b - 3072;  ob = lb; }
  else if (b < 8192)  { in = f1;    out = o_f1;  lb = b - 4096;  ob = lb; }
  else if (b < 12288) { in = f2;    out = o_f2;  lb = b - 8192;  ob = lb; }
  else                { in = src;   out = o_src; lb = b - 12288; ob = lb; }
  int i = lb * 256 + threadIdx.x;
  int o = ob * 256 + threadIdx.x;
  float4 v = ((const float4*)in)[i];
  ushort4 ov;
  ov.x = f2bf(v.x); ov.y = f2bf(v.y); ov.z = f2bf(v.z); ov.w = f2bf(v.w);
  ((ushort4*)out)[o] = ov;
}

// ---------------- GEMM (legacy 128x128, 2-barrier): C[M,N] = A @ W^T + bias --
// Kept for out-proj (split-K, small FLOP count).
// MODE 0: bf16 PARTIAL out per z-slice. MODE 1: bf16 out with ReLU.
template <int MODE, int SPLIT>
__global__ __launch_bounds__(256)
void gemm_bt(const u16* __restrict__ A, const u16* __restrict__ W,
             const float* __restrict__ bias,
             u16* __restrict__ outb,
             u16* __restrict__ qo, u16* __restrict__ ko, u16* __restrict__ vto,
             int M, int N, int K) {
  __shared__ u16 As[128 * 64];
  __shared__ u16 Bs[128 * 64];
  const int lane = threadIdx.x & 63;
  const int wave = threadIdx.x >> 6;
  const int lrow = lane & 15;
  const int lq = lane >> 4;
  const int tm = blockIdx.x * 128;
  const int tn = blockIdx.y * 128;
  const int wm = (wave >> 1) * 64;
  const int wn = (wave & 1) * 64;
  const int kc = K / SPLIT;
  const int kbeg = blockIdx.z * kc;
  f32x4 acc[4][4] = {};

  for (int k0 = kbeg; k0 < kbeg + kc; k0 += 64) {
#pragma unroll
    for (int c = 0; c < 4; ++c) {
      int chunk = wave * 256 + c * 64 + lane;
      int row = chunk >> 3;
      int sc = chunk & 7;
      int cc = sc ^ (row & 7);                   // swizzled source chunk
      u16* la = As + (size_t)(wave * 256 + c * 64) * 8;  // wave-uniform base
      u16* lb = Bs + (size_t)(wave * 256 + c * 64) * 8;
      async16(A + (size_t)(tm + row) * K + (k0 + cc * 8), la);
      async16(W + (size_t)(tn + row) * K + (k0 + cc * 8), lb);
    }
    __syncthreads();
#pragma unroll
    for (int h = 0; h < 2; ++h) {   // two 32-k halves per staged tile
      bf16x8 a_frag[4], b_frag[4];
#pragma unroll
      for (int i = 0; i < 4; ++i) {
        int row = wm + i * 16 + lrow;
        int sc = (h * 4 + lq) ^ (row & 7);
        a_frag[i] = *(const bf16x8*)(As + row * 64 + sc * 8);
      }
#pragma unroll
      for (int j = 0; j < 4; ++j) {
        int row = wn + j * 16 + lrow;
        int sc = (h * 4 + lq) ^ (row & 7);
        b_frag[j] = *(const bf16x8*)(Bs + row * 64 + sc * 8);
      }
#pragma unroll
      for (int i = 0; i < 4; ++i)
#pragma unroll
        for (int j = 0; j < 4; ++j)
          acc[i][j] = mfma16(a_frag[i], b_frag[j], acc[i][j]);
    }
    __syncthreads();
  }

  u16* outp = outb;
  if constexpr (MODE == 0) outp += (size_t)blockIdx.z * M * N;

#pragma unroll
  for (int i = 0; i < 4; ++i) {
#pragma unroll
    for (int j = 0; j < 4; ++j) {
      int col = tn + wn + j * 16 + lrow;
      float bv = (SPLIT == 1 || blockIdx.z == 0) ? bias[col] : 0.f;
#pragma unroll
      for (int r = 0; r < 4; ++r) {
        int row = tm + wm + i * 16 + lq * 4 + r;
        float v = acc[i][j][r] + bv;
        if constexpr (MODE == 0) {
          outp[(size_t)row * N + col] = f2bf(v);   // bf16 partial
        } else {
          outp[(size_t)row * N + col] = f2bf(fmaxf(v, 0.f));
        }
      }
    }
  }
}

// ---------------- GEMM 256x256, 8-phase counted-vmcnt schedule (T2+T3+T4+T5) --
// M=4096 fixed; per-z K chunk = 1024 fixed (16 k-tiles); Kfull is the row
// stride (Kfull = 1024*SPLIT). blockIdx.y = z (split-K slice). 512 threads =
// 8 waves (2M x 4N); per-wave C = 128x64 (8x4 16x16 frags). BK=64,
// double-buffered 128 KiB LDS (dynamic): As[2][256][64] | Bs[2][256][64],
// chunk-XOR swizzle. Schedule/safety/readiness comments as verified in R6.
// XCD-RECTANGLE swizzle (kept from R10: non-attn time improved ~1.1us):
// per XCD a 4tm x (NTN/2)tn rectangle so the per-XCD L2 footprint is
// A 2MB + W <=3-4MB instead of all 16 A-tiles. xcd = wg&7, loc = wg>>3:
//   tm_idx = (xcd&3)*4 + (loc&3), tn_idx = (xcd>>2)*(NTN/2) + (loc>>2).
// Bijective for all call sites (grids 192/256/64: NTN = 12/16/4, even).
// MODE 0: bf16 partial out per z. MODE 1: ReLU bf16 out. MODE 2: QKV scatter
// (V path writes via per-wave LDS transpose for full-line coalescing).
template <int MODE, int SPLIT>
__global__ __launch_bounds__(512, 2)
void gemm8p(const u16* __restrict__ A, const u16* __restrict__ W,
            const float* __restrict__ bias, u16* __restrict__ outb,
            u16* __restrict__ qo, u16* __restrict__ ko, u16* __restrict__ vto,
            int N, int Kfull) {
  extern __shared__ u16 lds[];
  constexpr int NTK = 16;         // k-tiles per z-slice (K chunk = 1024)
  constexpr int NG = NTK / 2;     // 8 groups
  u16* As = lds;                  // [2][256][64]
  u16* Bs = lds + 32768;
  const int tid = threadIdx.x;
  const int lane = tid & 63;
  const int wave = tid >> 6;
  const int lrow = lane & 15;
  const int lq = lane >> 4;
  const int wm = wave >> 2;       // 0..1
  const int wn = wave & 3;        // 0..3
  const int kbeg = blockIdx.y * 1024;   // z-slice K offset

  // XCD-rectangle swizzle (bijective; gridDim.x = 16*NTN, NTN even)
  const int wg = blockIdx.x;
  const int ntn2 = gridDim.x >> 5;      // NTN/2
  const int xcd = wg & 7, loc = wg >> 3;
  const int tm = ((xcd & 3) * 4 + (loc & 3)) * 256;
  const int tn = ((xcd >> 2) * ntn2 + (loc >> 2)) * 256;

  auto stage = [&](const u16* __restrict__ T, int trow0, int kt, int rbase,
                   u16* base) {
#pragma unroll
    for (int it = 0; it < 2; ++it) {
      int c = it * 512 + tid;
      int row = c >> 3, sc = c & 7, cc = sc ^ (row & 7);
      async16(T + (size_t)(trow0 + rbase + row) * Kfull + kbeg + kt * 64 + cc * 8,
              base + rbase * 64 + (it * 512 + wave * 64) * 8);
    }
  };
  auto ldA = [&](int buf, int m, int h) {
    int row = wm * 128 + m * 16 + lrow;
    int sc = (h * 4 + lq) ^ (row & 7);
    return *(const bf16x8*)(As + buf * 16384 + row * 64 + sc * 8);
  };
  auto ldB = [&](int buf, int n, int h) {
    int row = wn * 64 + n * 16 + lrow;
    int sc = (h * 4 + lq) ^ (row & 7);
    return *(const bf16x8*)(Bs + buf * 16384 + row * 64 + sc * 8);
  };

  f32x4 acc[8][4] = {};
  bf16x8 a[4][2], b[4][2];

  // prologue: t0 fully + t1.B0 + t1.A0 (order matters for the vmcnt account)
  stage(A, tm, 0, 0, As);
  stage(A, tm, 0, 128, As);
  stage(W, tn, 0, 0, Bs);
  stage(W, tn, 0, 128, Bs);
  stage(W, tn, 1, 0, Bs + 16384);
  stage(A, tm, 1, 0, As + 16384);
  asm volatile("s_waitcnt vmcnt(4)" ::: "memory");
  __builtin_amdgcn_s_barrier();

  for (int g = 0; g < NG; ++g) {
    const int t = 2 * g;
    const int t1k = t + 1;                            // always < NTK
    const int t2k = (t + 2 < NTK) ? t + 2 : NTK - 1;  // clamp (last group)
    const int t3k = (t + 3 < NTK) ? t + 3 : NTK - 1;

    // ---- P1: tile t (buf0) : read A0-3 + B0-1, MFMA Q(m0-3, n0-1) ----
#pragma unroll
    for (int m = 0; m < 4; ++m) { a[m][0] = ldA(0, m, 0); a[m][1] = ldA(0, m, 1); }
#pragma unroll
    for (int n = 0; n < 2; ++n) { b[n][0] = ldB(0, n, 0); b[n][1] = ldB(0, n, 1); }
    stage(A, tm, t1k, 128, As + 16384);   // (t+1).A1
    __builtin_amdgcn_s_barrier();
    asm volatile("s_waitcnt lgkmcnt(0)" ::: "memory");
    __builtin_amdgcn_s_setprio(1);
#pragma unroll
    for (int m = 0; m < 4; ++m)
#pragma unroll
      for (int n = 0; n < 2; ++n) {
        acc[m][n] = mfma16(a[m][0], b[n][0], acc[m][n]);
        acc[m][n] = mfma16(a[m][1], b[n][1], acc[m][n]);
      }
    __builtin_amdgcn_s_setprio(0);
    __builtin_amdgcn_s_barrier();

    // ---- P2: read B2-3, MFMA Q(m0-3, n2-3) ----
#pragma unroll
    for (int n = 0; n < 2; ++n) { b[2 + n][0] = ldB(0, 2 + n, 0); b[2 + n][1] = ldB(0, 2 + n, 1); }
    stage(W, tn, t1k, 128, Bs + 16384);   // (t+1).B1
    __builtin_amdgcn_s_barrier();
    asm volatile("s_waitcnt lgkmcnt(0)" ::: "memory");
    __builtin_amdgcn_s_setprio(1);
#pragma unroll
    for (int m = 0; m < 4; ++m)
#pragma unroll
      for (int n = 0; n < 2; ++n) {
        acc[m][2 + n] = mfma16(a[m][0], b[2 + n][0], acc[m][2 + n]);
        acc[m][2 + n] = mfma16(a[m][1], b[2 + n][1], acc[m][2 + n]);
      }
    __builtin_amdgcn_s_setprio(0);
    __builtin_amdgcn_s_barrier();

    // ---- P3: read A4-7 (reuse regs), MFMA Q(m4-7, n0-1) ----
#pragma unroll
    for (int m = 0; m < 4; ++m) { a[m][0] = ldA(0, 4 + m, 0); a[m][1] = ldA(0, 4 + m, 1); }
    stage(W, tn, t2k, 0, Bs);             // (t+2).B0
    __builtin_amdgcn_s_barrier();
    asm volatile("s_waitcnt lgkmcnt(0)" ::: "memory");
    __builtin_amdgcn_s_setprio(1);
#pragma unroll
    for (int m = 0; m < 4; ++m)
#pragma unroll
      for (int n = 0; n < 2; ++n) {
        acc[4 + m][n] = mfma16(a[m][0], b[n][0], acc[4 + m][n]);
        acc[4 + m][n] = mfma16(a[m][1], b[n][1], acc[4 + m][n]);
      }
    __builtin_amdgcn_s_setprio(0);
    __builtin_amdgcn_s_barrier();

    // ---- P4: no reads, MFMA Q(m4-7, n2-3); vmcnt guard for tile t+1 ----
    stage(A, tm, t2k, 0, As);             // (t+2).A0
    asm volatile("s_waitcnt vmcnt(4)" ::: "memory");
    __builtin_amdgcn_s_barrier();
    __builtin_amdgcn_s_setprio(1);
#pragma unroll
    for (int m = 0; m < 4; ++m)
#pragma unroll
      for (int n = 0; n < 2; ++n) {
        acc[4 + m][2 + n] = mfma16(a[m][0], b[2 + n][0], acc[4 + m][2 + n]);
        acc[4 + m][2 + n] = mfma16(a[m][1], b[2 + n][1], acc[4 + m][2 + n]);
      }
    __builtin_amdgcn_s_setprio(0);
    __builtin_amdgcn_s_barrier();

    // ---- P5: tile t+1 (buf1) : read A0-3 + B0-1, MFMA Q(m0-3, n0-1) ----
#pragma unroll
    for (int m = 0; m < 4; ++m) { a[m][0] = ldA(1, m, 0); a[m][1] = ldA(1, m, 1); }
#pragma unroll
    for (int n = 0; n < 2; ++n) { b[n][0] = ldB(1, n, 0); b[n][1] = ldB(1, n, 1); }
    stage(A, tm, t2k, 128, As);           // (t+2).A1
    __builtin_amdgcn_s_barrier();
    asm volatile("s_waitcnt lgkmcnt(0)" ::: "memory");
    __builtin_amdgcn_s_setprio(1);
#pragma unroll
    for (int m = 0; m < 4; ++m)
#pragma unroll
      for (int n = 0; n < 2; ++n) {
        acc[m][n] = mfma16(a[m][0], b[n][0], acc[m][n]);
        acc[m][n] = mfma16(a[m][1], b[n][1], acc[m][n]);
      }
    __builtin_amdgcn_s_setprio(0);
    __builtin_amdgcn_s_barrier();

    // ---- P6: read B2-3, MFMA Q(m0-3, n2-3) ----
#pragma unroll
    for (int n = 0; n < 2; ++n) { b[2 + n][0] = ldB(1, 2 + n, 0); b[2 + n][1] = ldB(1, 2 + n, 1); }
    stage(W, tn, t2k, 128, Bs);           // (t+2).B1
    __builtin_amdgcn_s_barrier();
    asm volatile("s_waitcnt lgkmcnt(0)" ::: "memory");
    __builtin_amdgcn_s_setprio(1);
#pragma unroll
    for (int m = 0; m < 4; ++m)
#pragma unroll
      for (int n = 0; n < 2; ++n) {
        acc[m][2 + n] = mfma16(a[m][0], b[2 + n][0], acc[m][2 + n]);
        acc[m][2 + n] = mfma16(a[m][1], b[2 + n][1], acc[m][2 + n]);
      }
    __builtin_amdgcn_s_setprio(0);
    __builtin_amdgcn_s_barrier();

    // ---- P7: read A4-7, MFMA Q(m4-7, n0-1) ----
#pragma unroll
    for (int m = 0; m < 4; ++m) { a[m][0] = ldA(1, 4 + m, 0); a[m][1] = ldA(1, 4 + m, 1); }
    stage(W, tn, t3k, 0, Bs + 16384);     // (t+3).B0
    __builtin_amdgcn_s_barrier();
    asm volatile("s_waitcnt lgkmcnt(0)" ::: "memory");
    __builtin_amdgcn_s_setprio(1);
#pragma unroll
    for (int m = 0; m < 4; ++m)
#pragma unroll
      for (int n = 0; n < 2; ++n) {
        acc[4 + m][n] = mfma16(a[m][0], b[n][0], acc[4 + m][n]);
        acc[4 + m][n] = mfma16(a[m][1], b[n][1], acc[4 + m][n]);
      }
    __builtin_amdgcn_s_setprio(0);
    __builtin_amdgcn_s_barrier();

    // ---- P8: no reads, MFMA Q(m4-7, n2-3); vmcnt guard for tile t+2 ----
    stage(A, tm, t3k, 0, As + 16384);     // (t+3).A0
    asm volatile("s_waitcnt vmcnt(4)" ::: "memory");
    __builtin_amdgcn_s_barrier();
    __builtin_amdgcn_s_setprio(1);
#pragma unroll
    for (int m = 0; m < 4; ++m)
#pragma unroll
      for (int n = 0; n < 2; ++n) {
        acc[4 + m][2 + n] = mfma16(a[m][0], b[2 + n][0], acc[4 + m][2 + n]);
        acc[4 + m][2 + n] = mfma16(a[m][1], b[2 + n][1], acc[4 + m][2 + n]);
      }
    __builtin_amdgcn_s_setprio(0);
    __builtin_amdgcn_s_barrier();
  }
  asm volatile("s_waitcnt vmcnt(0)" ::: "memory");  // drain redundant tail loads
  __builtin_amdgcn_s_barrier();   // ALL waves drained -> LDS reusable in epilogue

  if constexpr (MODE == 0) {
    u16* outp = outb + (size_t)blockIdx.y * 4096 * N;
#pragma unroll
    for (int m = 0; m < 8; ++m)
#pragma unroll
      for (int n = 0; n < 4; ++n) {
        int col = tn + wn * 64 + n * 16 + lrow;
        float bv = (SPLIT == 1 || blockIdx.y == 0) ? bias[col] : 0.f;
#pragma unroll
        for (int r = 0; r < 4; ++r) {
          int row = tm + wm * 128 + m * 16 + lq * 4 + r;
          outp[(size_t)row * N + col] = f2bf(acc[m][n][r] + bv);
        }
      }
  } else if constexpr (MODE == 1) {
#pragma unroll
    for (int m = 0; m < 8; ++m)
#pragma unroll
      for (int n = 0; n < 4; ++n) {
        int col = tn + wn * 64 + n * 16 + lrow;
        float bv = bias[col];
#pragma unroll
        for (int r = 0; r < 4; ++r) {
          int row = tm + wm * 128 + m * 16 + lq * 4 + r;
          outb[(size_t)row * N + col] = f2bf(fmaxf(acc[m][n][r] + bv, 0.f));
        }
      }
  } else {
    const int type = tn >> 10;                  // 0=q, 1=k, 2=v (block-uniform)
    if (type < 2) {
      u16* dst = (type == 0) ? qo : ko;
      const float scale = (type == 0) ? 0.1803368801f : 1.f;  // 1/8*log2e
#pragma unroll
      for (int n = 0; n < 4; ++n) {
        int idx = (tn & 1023) + wn * 64 + n * 16 + lrow;
        int hh = idx >> 6, c = idx & 63;
        float bv = bias[hh * 192 + type * 64 + c];
#pragma unroll
        for (int m = 0; m < 8; ++m) {
#pragma unroll
          for (int r = 0; r < 4; ++r) {
            int row = tm + wm * 128 + m * 16 + lq * 4 + r;
            int bb = row >> 11, s = row & 2047;
            dst[(((size_t)(bb * 16 + hh) * 2048 + s) << 6) + c] =
                f2bf((acc[m][n][r] + bv) * scale);
          }
        }
      }
    } else {
      // V: coalesced write via per-wave LDS transpose. Per (m-pair p, n):
      // transpose a 16-idx x 32-s tile in wave-private LDS so each store
      // instruction covers full 64B lines of vto's [bh][c][s] pages.
      u16* T = lds + wave * 640;            // [16 idx][40 s] u16 (pad 32->40)
      const int bb = tm >> 11;
      const int s_base = (tm & 2047) + wm * 128;
      const int idxl = lane & 15, sg = lane >> 4;
      const int idx2 = (tn & 1023) + wn * 64 + idxl;   // + n*16 added in loop
#pragma unroll
      for (int p = 0; p < 4; ++p) {
#pragma unroll
        for (int n = 0; n < 4; ++n) {
          int idx = (tn & 1023) + wn * 64 + n * 16 + lrow;
          int hh = idx >> 6, c = idx & 63;
          float bv = bias[hh * 192 + 128 + c];
          ushort4 lo, hi;
          lo.x = f2bf(acc[2 * p][n][0] + bv);
          lo.y = f2bf(acc[2 * p][n][1] + bv);
          lo.z = f2bf(acc[2 * p][n][2] + bv);
          lo.w = f2bf(acc[2 * p][n][3] + bv);
          hi.x = f2bf(acc[2 * p + 1][n][0] + bv);
          hi.y = f2bf(acc[2 * p + 1][n][1] + bv);
          hi.z = f2bf(acc[2 * p + 1][n][2] + bv);
          hi.w = f2bf(acc[2 * p + 1][n][3] + bv);
          *(ushort4*)(T + lrow * 40 + lq * 4) = lo;        // s_local = lq*4+r
          *(ushort4*)(T + lrow * 40 + 16 + lq * 4) = hi;   // s_local+16
          asm volatile("s_waitcnt lgkmcnt(0)" ::: "memory");
          int i2 = idx2 + n * 16;
          int hh2 = i2 >> 6, c2 = i2 & 63;
          uint4 v = *(const uint4*)(T + idxl * 40 + sg * 8);
          *(uint4*)(vto + (((size_t)(bb * 16 + hh2) * 64 + c2) << 11)
                        + s_base + p * 32 + sg * 8) = v;
          asm volatile("s_waitcnt lgkmcnt(0)" ::: "memory");  // reads done before next writes
        }
      }
    }
  }
}

// ---------------- Flash attention, 4-way KV-split, KVBLK=64, 2 Q-frags -----
// R11-proven inner-loop STRUCTURE preserved verbatim (per-half QK with long
// sacc chain -> pack -> PV fused across halves); only the tile parameter
// shrinks: KVBLK 128->64 so LDS = 32KB -> 4 blocks/CU (grid 1024 = 4/CU,
// 32 waves/CU) vs the old 2/CU LDS cap. Theory: attn is latency/stall-bound
// (R7-R11 counters: ~19% occupancy, MfmaUtil ~45, bank-conflict constant);
// doubling resident waves attacks the stall directly without touching the
// delicate compiler schedule (R4/R10 inner-loop edits both regressed).
__global__ __launch_bounds__(512)
void attn_kernel(const u16* __restrict__ Q, const u16* __restrict__ K,
                 const u16* __restrict__ Vt,
                 u16* __restrict__ o_part, float* __restrict__ l_part) {
  extern __shared__ u16 smem[];
  u16* Ks = smem;            // [2][64][64], chunk-swizzled
  u16* Vs = smem + 8192;     // [2][64][64], chunk-swizzled ([hd][key])
  const int tid = threadIdx.x;
  const int lane = tid & 63;
  const int wave = tid >> 6;      // 0..7
  const int wq = wave & 3;        // staging wave-within-role
  const int role = wave >> 2;     // 0: stage K, 1: stage Vt
  const int lrow = lane & 15;
  const int q = lane >> 4;
  const int bh = blockIdx.x & 31;        // XCD-affine
  const int qb = (blockIdx.x >> 5) & 7;  // 256 q-rows per block
  const int kvh = blockIdx.x >> 8;       // key quarter (0..3)
  const u16* Qp = Q + ((size_t)bh * 2048 + qb * 256) * 64;
  const u16* Kp = K + (size_t)bh * 2048 * 64;
  const u16* Vp = Vt + (size_t)bh * 64 * 2048;

  // two Q fragments per wave: rows wave*16 and 128 + wave*16
  bf16x8 qf[2][2];
#pragma unroll
  for (int h2 = 0; h2 < 2; ++h2)
#pragma unroll
    for (int kk = 0; kk < 2; ++kk)
      qf[h2][kk] = *(const bf16x8*)(Qp + (h2 * 128 + wave * 16 + lrow) * 64 +
                                    kk * 32 + q * 8);

  const s16x4 ones = {(short)0x3F80, (short)0x3F80, (short)0x3F80, (short)0x3F80};
  f32x4 oacc[2][4] = {};
  f32x4 lacc[2] = {};

  auto stage = [&](int kb, int buf) {
    if (role == 0) {
      // waves 0-3 stage K tile [64 keys][64 hd]: 512 chunks
#pragma unroll
      for (int t = 0; t < 2; ++t) {
        int c = wq * 128 + t * 64 + lane;
        int row = c >> 3, sc = c & 7;
        int cc = sc ^ (row & 7);
        async16(Kp + (size_t)(kb * 64 + row) * 64 + cc * 8,
                Ks + buf * 4096 + (size_t)(wq * 128 + t * 64) * 8);
      }
    } else {
      // waves 4-7 stage Vt tile [64 hd][64 keys]: 512 chunks
#pragma unroll
      for (int t = 0; t < 2; ++t) {
        int c = wq * 128 + t * 64 + lane;
        int row = c >> 3, sc = c & 7;
        int cc = sc ^ (row & 7);
        async16(Vp + (size_t)row * 2048 + kb * 64 + cc * 8,
                Vs + buf * 4096 + (size_t)(wq * 128 + t * 64) * 8);
      }
    }
  };

  const int kb0 = kvh * 8;    // 32 key-tiles of 64; 8 per quarter
  stage(kb0, 0);
  asm volatile("s_waitcnt vmcnt(0)" ::: "memory");
  __builtin_amdgcn_s_barrier();

  for (int i = 0; i < 8; ++i) {
    const int buf = i & 1;
    if (i < 7) stage(kb0 + i + 1, buf ^ 1);   // prefetch next tile
    const u16* Kb = Ks + buf * 4096;
    const u16* Vb = Vs + buf * 4096;

    // ---- QK^T + exp per half (proven structure), keep both halves' P ----
    s16x4 pa2[2][4];
#pragma unroll
    for (int h2 = 0; h2 < 2; ++h2) {
      f32x4 sacc[4] = {};
#pragma unroll
      for (int j = 0; j < 4; ++j) {
#pragma unroll
        for (int kk = 0; kk < 2; ++kk) {
          int row = j * 16 + lrow;
          int sc = (kk * 4 + q) ^ (row & 7);
          bf16x8 kf = *(const bf16x8*)(Kb + row * 64 + sc * 8);
          sacc[j] = mfma16(kf, qf[h2][kk], sacc[j]);
        }
      }
#pragma unroll
      for (int j = 0; j < 4; ++j) {
        float p0 = exp2_fast(sacc[j][0]);
        float p1 = exp2_fast(sacc[j][1]);
        float p2 = exp2_fast(sacc[j][2]);
        float p3 = exp2_fast(sacc[j][3]);
        u32x2 pw;
        pw.x = pk_bf_trunc(p0, p1);
        pw.y = pk_bf_trunc(p2, p3);
        pa2[h2][j] = __builtin_bit_cast(s16x4, pw);
      }
    }

    // ---- PV + denominator, FUSED: each vb read once, feeds both halves ----
#pragma unroll
    for (int j = 0; j < 4; ++j) {
      lacc[0] = mfma_pv(pa2[0][j], ones, lacc[0]);
      lacc[1] = mfma_pv(pa2[1][j], ones, lacc[1]);
#pragma unroll
      for (int jn = 0; jn < 4; ++jn) {
        int row = jn * 16 + lrow;
        int sc = (j * 2 + (q >> 1)) ^ (row & 7);
        s16x4 vb = *(const s16x4*)(Vb + row * 64 + sc * 8 + (q & 1) * 4);
        oacc[0][jn] = mfma_pv(pa2[0][j], vb, oacc[0][jn]);
        oacc[1][jn] = mfma_pv(pa2[1][j], vb, oacc[1][jn]);
      }
    }

    if (i < 7) {
      asm volatile("s_waitcnt vmcnt(0)" ::: "memory");  // prefetch landed
      __builtin_amdgcn_s_barrier();                     // all reads of buf done
    }
  }

  // write bf16 O-partials (pre-division) + fp32 l-partials
  const int b = bh >> 4, h = bh & 15;
  u16* op = o_part + (size_t)kvh * 4096 * 1024;
  float* lp = l_part + kvh * 65536 + bh * 2048;
#pragma unroll
  for (int h2 = 0; h2 < 2; ++h2) {
#pragma unroll
    for (int r = 0; r < 4; ++r) {
      int s = qb * 256 + h2 * 128 + wave * 16 + q * 4 + r;
      if (lrow == 0) lp[s] = lacc[h2][r];
      size_t base = ((size_t)(b * 2048 + s)) * 1024 + h * 64;
#pragma unroll
      for (int jn = 0; jn < 4; ++jn)
        op[base + jn * 16 + lrow] = f2bf(oacc[h2][jn][r]);
    }
  }
}

// ---------------- combine the four KV quarters: ctx = sum O / sum l --------
__global__ __launch_bounds__(256)
void attn_combine(const u16* __restrict__ o_part, const float* __restrict__ l_part,
                  u16* __restrict__ ctx) {
  const int t = blockIdx.x;            // token: b = t>>11, s = t&2047
  const int tid = threadIdx.x;
  __shared__ float linv[16];
  if (tid < 16) {
    int b = t >> 11, s = t & 2047;
    int bh = b * 16 + tid;
    float l = 0.f;
#pragma unroll
    for (int p = 0; p < 4; ++p) l += l_part[p * 65536 + bh * 2048 + s];
    linv[tid] = 1.f / l;
  }
  __syncthreads();
  size_t base = (size_t)t * 1024;
  float li = linv[tid >> 4];           // head of d = tid*4 (4-aligned, one head)
  float sx = 0.f, sy = 0.f, sz = 0.f, sw = 0.f;
#pragma unroll
  for (int p = 0; p < 4; ++p) {
    ushort4 a = ((const ushort4*)(o_part + (size_t)p * 4096 * 1024 + base))[tid];
    sx += bf2f(a.x); sy += bf2f(a.y); sz += bf2f(a.z); sw += bf2f(a.w);
  }
  ushort4 o;
  o.x = f2bf(sx * li);
  o.y = f2bf(sy * li);
  o.z = f2bf(sz * li);
  o.w = f2bf(sw * li);
  ((ushort4*)(ctx + base))[tid] = o;
}

// ---------------- LayerNorm over D=1024, fused residual + split-K reduce ----
// x = x1 + sum_{p<P} x2[p]  (x2 partials are bf16, M*N apart). Vectorized:
// thread t owns 4 consecutive elements (float4 / ushort4 loads+stores).
template <int P>
__global__ __launch_bounds__(256)
void ln_kernel(const float* __restrict__ x1, const u16* __restrict__ x2,
               const float* __restrict__ g, const float* __restrict__ bb,
               float* __restrict__ outf, u16* __restrict__ outb) {
  const int t = blockIdx.x;
  const int tid = threadIdx.x;
  const int lane = tid & 63, wave = tid >> 6;
  const size_t base = (size_t)t * 1024;
  const size_t pstride = 4096ull * 1024;
  float4 v = ((const float4*)(x1 + base))[tid];
#pragma unroll
  for (int p = 0; p < P; ++p) {
    ushort4 u = ((const ushort4*)(x2 + p * pstride + base))[tid];
    v.x += bf2f(u.x); v.y += bf2f(u.y); v.z += bf2f(u.z); v.w += bf2f(u.w);
  }
  float s = v.x + v.y + v.z + v.w;
  float s2 = v.x * v.x + v.y * v.y + v.z * v.z + v.w * v.w;
#pragma unroll
  for (int d = 1; d < 64; d <<= 1) {
    s += __shfl_xor(s, d);
    s2 += __shfl_xor(s2, d);
  }
  __shared__ float red[8];
  if (lane == 0) { red[wave] = s; red[4 + wave] = s2; }
  __syncthreads();
  s = red[0] + red[1] + red[2] + red[3];
  s2 = red[4] + red[5] + red[6] + red[7];
  float mean = s * (1.f / 1024.f);
  float var = s2 * (1.f / 1024.f) - mean * mean;
  float rstd = rsqrtf(var + 1e-5f);
  float4 gv = ((const float4*)g)[tid];
  float4 bv = ((const float4*)bb)[tid];
  float4 y;
  y.x = (v.x - mean) * rstd * gv.x + bv.x;
  y.y = (v.y - mean) * rstd * gv.y + bv.y;
  y.z = (v.z - mean) * rstd * gv.z + bv.z;
  y.w = (v.w - mean) * rstd * gv.w + bv.w;
  ((float4*)(outf + base))[tid] = y;
  if (outb) {
    ushort4 ob;
    ob.x = f2bf(y.x); ob.y = f2bf(y.y); ob.z = f2bf(y.z); ob.w = f2bf(y.w);
    ((ushort4*)(outb + base))[tid] = ob;
  }
}

// ---------------- launch ----------------
extern "C" void kernel_launch(void* const* d_in, const int* in_sizes, int n_in,
                              void* d_out, int out_size, void* d_ws, size_t ws_size,
                              hipStream_t stream) {
  const float* src    = (const float*)d_in[0];
  const float* qkv_w  = (const float*)d_in[1];
  const float* qkv_b  = (const float*)d_in[2];
  const float* out_w  = (const float*)d_in[3];
  const float* out_b  = (const float*)d_in[4];
  const float* ffn_w1 = (const float*)d_in[5];
  const float* ffn_b1 = (const float*)d_in[6];
  const float* ffn_w2 = (const float*)d_in[7];
  const float* ffn_b2 = (const float*)d_in[8];
  const float* ln1_g  = (const float*)d_in[9];
  const float* ln1_b  = (const float*)d_in[10];
  const float* ln2_g  = (const float*)d_in[11];
  const float* ln2_b  = (const float*)d_in[12];

  char* ws = (char*)d_ws;
  size_t off = 0;
  auto alloc = [&](size_t bytes) -> void* {
    void* p = ws + off;
    off += (bytes + 255) & ~(size_t)255;
    return p;
  };
  u16* wqkv = (u16*)alloc(3072ull * 1024 * 2);
  u16* wout = (u16*)alloc(1024ull * 1024 * 2);
  u16* wf1  = (u16*)alloc(4096ull * 1024 * 2);
  u16* wf2  = (u16*)alloc(1024ull * 4096 * 2);
  u16* srcb = (u16*)alloc(4096ull * 1024 * 2);
  u16* qb_  = (u16*)alloc(32ull * 2048 * 64 * 2);
  u16* kb_  = (u16*)alloc(32ull * 2048 * 64 * 2);
  u16* vtb  = (u16*)alloc(32ull * 64 * 2048 * 2);
  u16* opart = (u16*)alloc(4ull * 4096 * 1024 * 2);  // 4 bf16 O partials
  float* lpart = (float*)alloc(4ull * 65536 * 4);    // 4 fp32 l partials
  u16* ctxb = (u16*)alloc(4096ull * 1024 * 2);
  u16* mha  = (u16*)alloc(4ull * 4096 * 1024 * 2);   // 4 bf16 split-K partials
  float* aggf = (float*)alloc(4096ull * 1024 * 4);
  u16* aggb = (u16*)alloc(4096ull * 1024 * 2);
  u16* hb   = (u16*)alloc(4096ull * 4096 * 2);
  u16* ffnf = (u16*)alloc(4ull * 4096 * 1024 * 2);   // 4 bf16 split-K partials

  // allow dynamic LDS beyond default (once per process)
  static bool attr_done = false;
  if (!attr_done) {
    auto* kq = gemm8p<2, 1>;
    auto* kf = gemm8p<1, 1>;
    auto* k2 = gemm8p<0, 4>;
    hipFuncSetAttribute(reinterpret_cast<const void*>(kq),
                        hipFuncAttributeMaxDynamicSharedMemorySize, 131072);
    hipFuncSetAttribute(reinterpret_cast<const void*>(kf),
                        hipFuncAttributeMaxDynamicSharedMemorySize, 131072);
    hipFuncSetAttribute(reinterpret_cast<const void*>(k2),
                        hipFuncAttributeMaxDynamicSharedMemorySize, 131072);
    hipFuncSetAttribute(reinterpret_cast<const void*>(attn_kernel),
                        hipFuncAttributeMaxDynamicSharedMemorySize, 65536);
    attr_done = true;
  }

  // fused fp32 -> bf16 converts (single launch; qkv_w rows permuted to grouped order)
  cvt_all<<<16384, 256, 0, stream>>>(qkv_w, out_w, ffn_w1, ffn_w2, src,
                                     wqkv, wout, wf1, wf2, srcb);

  // QKV projection + grouped head scatter (q scaled, v transposed): 8-phase 256^2
  gemm8p<2, 1><<<dim3(192, 1), 512, 131072, stream>>>(srcb, wqkv, qkv_b, nullptr,
                                                      qb_, kb_, vtb, 3072, 1024);
  // flash attention, 4-way KV-split, KVBLK=64, 4 blocks/CU -> O/l partials
  attn_kernel<<<1024, 512, 32768, stream>>>(qb_, kb_, vtb, opart, lpart);
  // combine partials -> ctx [B,S,D] bf16
  attn_combine<<<4096, 256, 0, stream>>>(opart, lpart, ctxb);
  // output projection -> mha bf16 partials (split-K=4, no atomics)
  gemm_bt<0, 4><<<dim3(32, 8, 4), 256, 0, stream>>>(ctxb, wout, out_b, mha,
                                                    nullptr, nullptr, nullptr, 4096, 1024, 1024);
  // LN1(src + sum mha partials) -> agg fp32 + bf16
  ln_kernel<4><<<4096, 256, 0, stream>>>(src, mha, ln1_g, ln1_b, aggf, aggb);
  // FFN1 + ReLU -> h bf16: 8-phase 256^2
  gemm8p<1, 1><<<dim3(256, 1), 512, 131072, stream>>>(aggb, wf1, ffn_b1, hb,
                                                      nullptr, nullptr, nullptr, 4096, 1024);
  // FFN2 -> ffn bf16 partials: 8-phase 256^2, split-K=4 (grid 64x4 = 256 blocks)
  gemm8p<0, 4><<<dim3(64, 4), 512, 131072, stream>>>(hb, wf2, ffn_b2, ffnf,
                                                     nullptr, nullptr, nullptr, 1024, 4096);
  // LN2(agg + sum ffn partials) -> d_out fp32
  ln_kernel<4><<<4096, 256, 0, stream>>>(aggf, ffnf, ln2_g, ln2_b, (float*)d_out, nullptr);
}

// Round 14
// 345.321 us; speedup vs baseline: 1.0397x; 1.0397x over previous
//
#include <hip/hip_runtime.h>

// EncoderBlock: B=2, S=2048, D=1024, H=16, HD=64, F=4096, M=B*S=4096 tokens.

typedef unsigned short u16;
typedef unsigned int u32;
typedef __attribute__((ext_vector_type(8))) __bf16 bf16x8;
typedef __attribute__((ext_vector_type(4))) float f32x4;
typedef __attribute__((ext_vector_type(4))) short s16x4;
typedef __attribute__((ext_vector_type(2))) u32 u32x2;

__device__ __forceinline__ u16 f2bf(float f) {
  u32 u = __float_as_uint(f);
  u += 0x7fffu + ((u >> 16) & 1u);   // RNE
  return (u16)(u >> 16);
}

__device__ __forceinline__ float bf2f(u16 h) {
  return __uint_as_float((u32)h << 16);
}

__device__ __forceinline__ u32 pk_bf_trunc(float a, float b) {
  return (__float_as_uint(a) >> 16) | (__float_as_uint(b) & 0xffff0000u);
}

// Schraudolph-style exp2: 2 full-rate VALU ops vs quarter-rate v_exp_f32.
__device__ __forceinline__ float exp2_fast(float x) {
  float t = __builtin_fmaf(x, 8388608.0f, 1064992506.0f);
  return __int_as_float((int)t);
}

__device__ __forceinline__ void async16(const void* g, void* l) {
  __builtin_amdgcn_global_load_lds((__attribute__((address_space(1))) void*)g,
                                   (__attribute__((address_space(3))) void*)l,
                                   16, 0, 0);
}

__device__ __forceinline__ f32x4 mfma16(bf16x8 a, bf16x8 b, f32x4 c) {
  return __builtin_amdgcn_mfma_f32_16x16x32_bf16(a, b, c, 0, 0, 0);
}

__device__ __forceinline__ f32x4 mfma_pv(s16x4 a, s16x4 b, f32x4 c) {
#if __has_builtin(__builtin_amdgcn_mfma_f32_16x16x16bf16_1k)
  return __builtin_amdgcn_mfma_f32_16x16x16bf16_1k(a, b, c, 0, 0, 0);
#else
  f32x4 d;
  asm("v_mfma_f32_16x16x16_bf16 %0, %1, %2, %3" : "=v"(d) : "v"(a), "v"(b), "v"(c));
  return d;
#endif
}

// ------- fused fp32 -> bf16 convert for all 5 tensors (1 launch) -------
// regions (1024-elem blocks): qkv_w 3072 | out_w 1024 | f1 4096 | f2 4096 | src 4096
// qkv_w rows are PERMUTED on write into grouped order [q 1024 | k 1024 | v 1024].
__global__ __launch_bounds__(256)
void cvt_all(const float* __restrict__ qkv_w, const float* __restrict__ out_w,
             const float* __restrict__ f1, const float* __restrict__ f2,
             const float* __restrict__ src,
             u16* __restrict__ o_qkv, u16* __restrict__ o_out,
             u16* __restrict__ o_f1, u16* __restrict__ o_f2,
             u16* __restrict__ o_src) {
  int b = blockIdx.x;
  const float* in;
  u16* out;
  int lb, ob;
  if (b < 3072) {
    int h = b / 192, c = b - h * 192;
    ob = (c < 64) ? h * 64 + c : (c < 128) ? 1024 + h * 64 + (c - 64)
                                           : 2048 + h * 64 + (c - 128);
    in = qkv_w; out = o_qkv; lb = b;
  }
  else if (b < 4096)  { in = out_w; out = o_out; lb = b - 3072;  ob = lb; }
  else if (b < 8192)  { in = f1;    out = o_f1;  lb = b - 4096;  ob = lb; }
  else if (b < 12288) { in = f2;    out = o_f2;  lb = b - 8192;  ob = lb; }
  else                { in = src;   out = o_src; lb = b - 12288; ob = lb; }
  int i = lb * 256 + threadIdx.x;
  int o = ob * 256 + threadIdx.x;
  float4 v = ((const float4*)in)[i];
  ushort4 ov;
  ov.x = f2bf(v.x); ov.y = f2bf(v.y); ov.z = f2bf(v.z); ov.w = f2bf(v.w);
  ((ushort4*)out)[o] = ov;
}

// ---------------- GEMM (legacy 128x128, 2-barrier): C[M,N] = A @ W^T + bias --
// Kept for out-proj (split-K, small FLOP count).
// MODE 0: bf16 PARTIAL out per z-slice. MODE 1: bf16 out with ReLU.
template <int MODE, int SPLIT>
__global__ __launch_bounds__(256)
void gemm_bt(const u16* __restrict__ A, const u16* __restrict__ W,
             const float* __restrict__ bias,
             u16* __restrict__ outb,
             u16* __restrict__ qo, u16* __restrict__ ko, u16* __restrict__ vto,
             int M, int N, int K) {
  __shared__ u16 As[128 * 64];
  __shared__ u16 Bs[128 * 64];
  const int lane = threadIdx.x & 63;
  const int wave = threadIdx.x >> 6;
  const int lrow = lane & 15;
  const int lq = lane >> 4;
  const int tm = blockIdx.x * 128;
  const int tn = blockIdx.y * 128;
  const int wm = (wave >> 1) * 64;
  const int wn = (wave & 1) * 64;
  const int kc = K / SPLIT;
  const int kbeg = blockIdx.z * kc;
  f32x4 acc[4][4] = {};

  for (int k0 = kbeg; k0 < kbeg + kc; k0 += 64) {
#pragma unroll
    for (int c = 0; c < 4; ++c) {
      int chunk = wave * 256 + c * 64 + lane;
      int row = chunk >> 3;
      int sc = chunk & 7;
      int cc = sc ^ (row & 7);                   // swizzled source chunk
      u16* la = As + (size_t)(wave * 256 + c * 64) * 8;  // wave-uniform base
      u16* lb = Bs + (size_t)(wave * 256 + c * 64) * 8;
      async16(A + (size_t)(tm + row) * K + (k0 + cc * 8), la);
      async16(W + (size_t)(tn + row) * K + (k0 + cc * 8), lb);
    }
    __syncthreads();
#pragma unroll
    for (int h = 0; h < 2; ++h) {   // two 32-k halves per staged tile
      bf16x8 a_frag[4], b_frag[4];
#pragma unroll
      for (int i = 0; i < 4; ++i) {
        int row = wm + i * 16 + lrow;
        int sc = (h * 4 + lq) ^ (row & 7);
        a_frag[i] = *(const bf16x8*)(As + row * 64 + sc * 8);
      }
#pragma unroll
      for (int j = 0; j < 4; ++j) {
        int row = wn + j * 16 + lrow;
        int sc = (h * 4 + lq) ^ (row & 7);
        b_frag[j] = *(const bf16x8*)(Bs + row * 64 + sc * 8);
      }
#pragma unroll
      for (int i = 0; i < 4; ++i)
#pragma unroll
        for (int j = 0; j < 4; ++j)
          acc[i][j] = mfma16(a_frag[i], b_frag[j], acc[i][j]);
    }
    __syncthreads();
  }

  u16* outp = outb;
  if constexpr (MODE == 0) outp += (size_t)blockIdx.z * M * N;

#pragma unroll
  for (int i = 0; i < 4; ++i) {
#pragma unroll
    for (int j = 0; j < 4; ++j) {
      int col = tn + wn + j * 16 + lrow;
      float bv = (SPLIT == 1 || blockIdx.z == 0) ? bias[col] : 0.f;
#pragma unroll
      for (int r = 0; r < 4; ++r) {
        int row = tm + wm + i * 16 + lq * 4 + r;
        float v = acc[i][j][r] + bv;
        if constexpr (MODE == 0) {
          outp[(size_t)row * N + col] = f2bf(v);   // bf16 partial
        } else {
          outp[(size_t)row * N + col] = f2bf(fmaxf(v, 0.f));
        }
      }
    }
  }
}

// ---------------- GEMM 256x256, 8-phase counted-vmcnt schedule (T2+T3+T4+T5) --
// M=4096 fixed; per-z K chunk = 1024 fixed (16 k-tiles); Kfull is the row
// stride (Kfull = 1024*SPLIT). blockIdx.y = z (split-K slice). 512 threads =
// 8 waves (2M x 4N); per-wave C = 128x64 (8x4 16x16 frags). BK=64,
// double-buffered 128 KiB LDS (dynamic): As[2][256][64] | Bs[2][256][64],
// chunk-XOR swizzle. Schedule/safety/readiness comments as verified in R6.
// XCD-RECTANGLE swizzle: per XCD a 4tm x (NTN/2)tn rectangle so the per-XCD
// L2 footprint is A 2MB + W <=3-4MB (R13 counters: QKV FETCH 42.6->25.1MB).
// xcd = wg&7, loc = wg>>3: tm_idx = (xcd&3)*4 + (loc&3),
// tn_idx = (xcd>>2)*(NTN/2) + (loc>>2). Bijective (grids 192/256/64).
// MODE 0: bf16 partial out per z. MODE 1: ReLU bf16 out. MODE 2: QKV scatter
// (V path writes via per-wave LDS transpose for full-line coalescing).
template <int MODE, int SPLIT>
__global__ __launch_bounds__(512, 2)
void gemm8p(const u16* __restrict__ A, const u16* __restrict__ W,
            const float* __restrict__ bias, u16* __restrict__ outb,
            u16* __restrict__ qo, u16* __restrict__ ko, u16* __restrict__ vto,
            int N, int Kfull) {
  extern __shared__ u16 lds[];
  constexpr int NTK = 16;         // k-tiles per z-slice (K chunk = 1024)
  constexpr int NG = NTK / 2;     // 8 groups
  u16* As = lds;                  // [2][256][64]
  u16* Bs = lds + 32768;
  const int tid = threadIdx.x;
  const int lane = tid & 63;
  const int wave = tid >> 6;
  const int lrow = lane & 15;
  const int lq = lane >> 4;
  const int wm = wave >> 2;       // 0..1
  const int wn = wave & 3;        // 0..3
  const int kbeg = blockIdx.y * 1024;   // z-slice K offset

  // XCD-rectangle swizzle (bijective; gridDim.x = 16*NTN, NTN even)
  const int wg = blockIdx.x;
  const int ntn2 = gridDim.x >> 5;      // NTN/2
  const int xcd = wg & 7, loc = wg >> 3;
  const int tm = ((xcd & 3) * 4 + (loc & 3)) * 256;
  const int tn = ((xcd >> 2) * ntn2 + (loc >> 2)) * 256;

  auto stage = [&](const u16* __restrict__ T, int trow0, int kt, int rbase,
                   u16* base) {
#pragma unroll
    for (int it = 0; it < 2; ++it) {
      int c = it * 512 + tid;
      int row = c >> 3, sc = c & 7, cc = sc ^ (row & 7);
      async16(T + (size_t)(trow0 + rbase + row) * Kfull + kbeg + kt * 64 + cc * 8,
              base + rbase * 64 + (it * 512 + wave * 64) * 8);
    }
  };
  auto ldA = [&](int buf, int m, int h) {
    int row = wm * 128 + m * 16 + lrow;
    int sc = (h * 4 + lq) ^ (row & 7);
    return *(const bf16x8*)(As + buf * 16384 + row * 64 + sc * 8);
  };
  auto ldB = [&](int buf, int n, int h) {
    int row = wn * 64 + n * 16 + lrow;
    int sc = (h * 4 + lq) ^ (row & 7);
    return *(const bf16x8*)(Bs + buf * 16384 + row * 64 + sc * 8);
  };

  f32x4 acc[8][4] = {};
  bf16x8 a[4][2], b[4][2];

  // prologue: t0 fully + t1.B0 + t1.A0 (order matters for the vmcnt account)
  stage(A, tm, 0, 0, As);
  stage(A, tm, 0, 128, As);
  stage(W, tn, 0, 0, Bs);
  stage(W, tn, 0, 128, Bs);
  stage(W, tn, 1, 0, Bs + 16384);
  stage(A, tm, 1, 0, As + 16384);
  asm volatile("s_waitcnt vmcnt(4)" ::: "memory");
  __builtin_amdgcn_s_barrier();

  for (int g = 0; g < NG; ++g) {
    const int t = 2 * g;
    const int t1k = t + 1;                            // always < NTK
    const int t2k = (t + 2 < NTK) ? t + 2 : NTK - 1;  // clamp (last group)
    const int t3k = (t + 3 < NTK) ? t + 3 : NTK - 1;

    // ---- P1: tile t (buf0) : read A0-3 + B0-1, MFMA Q(m0-3, n0-1) ----
#pragma unroll
    for (int m = 0; m < 4; ++m) { a[m][0] = ldA(0, m, 0); a[m][1] = ldA(0, m, 1); }
#pragma unroll
    for (int n = 0; n < 2; ++n) { b[n][0] = ldB(0, n, 0); b[n][1] = ldB(0, n, 1); }
    stage(A, tm, t1k, 128, As + 16384);   // (t+1).A1
    __builtin_amdgcn_s_barrier();
    asm volatile("s_waitcnt lgkmcnt(0)" ::: "memory");
    __builtin_amdgcn_s_setprio(1);
#pragma unroll
    for (int m = 0; m < 4; ++m)
#pragma unroll
      for (int n = 0; n < 2; ++n) {
        acc[m][n] = mfma16(a[m][0], b[n][0], acc[m][n]);
        acc[m][n] = mfma16(a[m][1], b[n][1], acc[m][n]);
      }
    __builtin_amdgcn_s_setprio(0);
    __builtin_amdgcn_s_barrier();

    // ---- P2: read B2-3, MFMA Q(m0-3, n2-3) ----
#pragma unroll
    for (int n = 0; n < 2; ++n) { b[2 + n][0] = ldB(0, 2 + n, 0); b[2 + n][1] = ldB(0, 2 + n, 1); }
    stage(W, tn, t1k, 128, Bs + 16384);   // (t+1).B1
    __builtin_amdgcn_s_barrier();
    asm volatile("s_waitcnt lgkmcnt(0)" ::: "memory");
    __builtin_amdgcn_s_setprio(1);
#pragma unroll
    for (int m = 0; m < 4; ++m)
#pragma unroll
      for (int n = 0; n < 2; ++n) {
        acc[m][2 + n] = mfma16(a[m][0], b[2 + n][0], acc[m][2 + n]);
        acc[m][2 + n] = mfma16(a[m][1], b[2 + n][1], acc[m][2 + n]);
      }
    __builtin_amdgcn_s_setprio(0);
    __builtin_amdgcn_s_barrier();

    // ---- P3: read A4-7 (reuse regs), MFMA Q(m4-7, n0-1) ----
#pragma unroll
    for (int m = 0; m < 4; ++m) { a[m][0] = ldA(0, 4 + m, 0); a[m][1] = ldA(0, 4 + m, 1); }
    stage(W, tn, t2k, 0, Bs);             // (t+2).B0
    __builtin_amdgcn_s_barrier();
    asm volatile("s_waitcnt lgkmcnt(0)" ::: "memory");
    __builtin_amdgcn_s_setprio(1);
#pragma unroll
    for (int m = 0; m < 4; ++m)
#pragma unroll
      for (int n = 0; n < 2; ++n) {
        acc[4 + m][n] = mfma16(a[m][0], b[n][0], acc[4 + m][n]);
        acc[4 + m][n] = mfma16(a[m][1], b[n][1], acc[4 + m][n]);
      }
    __builtin_amdgcn_s_setprio(0);
    __builtin_amdgcn_s_barrier();

    // ---- P4: no reads, MFMA Q(m4-7, n2-3); vmcnt guard for tile t+1 ----
    stage(A, tm, t2k, 0, As);             // (t+2).A0
    asm volatile("s_waitcnt vmcnt(4)" ::: "memory");
    __builtin_amdgcn_s_barrier();
    __builtin_amdgcn_s_setprio(1);
#pragma unroll
    for (int m = 0; m < 4; ++m)
#pragma unroll
      for (int n = 0; n < 2; ++n) {
        acc[4 + m][2 + n] = mfma16(a[m][0], b[2 + n][0], acc[4 + m][2 + n]);
        acc[4 + m][2 + n] = mfma16(a[m][1], b[2 + n][1], acc[4 + m][2 + n]);
      }
    __builtin_amdgcn_s_setprio(0);
    __builtin_amdgcn_s_barrier();

    // ---- P5: tile t+1 (buf1) : read A0-3 + B0-1, MFMA Q(m0-3, n0-1) ----
#pragma unroll
    for (int m = 0; m < 4; ++m) { a[m][0] = ldA(1, m, 0); a[m][1] = ldA(1, m, 1); }
#pragma unroll
    for (int n = 0; n < 2; ++n) { b[n][0] = ldB(1, n, 0); b[n][1] = ldB(1, n, 1); }
    stage(A, tm, t2k, 128, As);           // (t+2).A1
    __builtin_amdgcn_s_barrier();
    asm volatile("s_waitcnt lgkmcnt(0)" ::: "memory");
    __builtin_amdgcn_s_setprio(1);
#pragma unroll
    for (int m = 0; m < 4; ++m)
#pragma unroll
      for (int n = 0; n < 2; ++n) {
        acc[m][n] = mfma16(a[m][0], b[n][0], acc[m][n]);
        acc[m][n] = mfma16(a[m][1], b[n][1], acc[m][n]);
      }
    __builtin_amdgcn_s_setprio(0);
    __builtin_amdgcn_s_barrier();

    // ---- P6: read B2-3, MFMA Q(m0-3, n2-3) ----
#pragma unroll
    for (int n = 0; n < 2; ++n) { b[2 + n][0] = ldB(1, 2 + n, 0); b[2 + n][1] = ldB(1, 2 + n, 1); }
    stage(W, tn, t2k, 128, Bs);           // (t+2).B1
    __builtin_amdgcn_s_barrier();
    asm volatile("s_waitcnt lgkmcnt(0)" ::: "memory");
    __builtin_amdgcn_s_setprio(1);
#pragma unroll
    for (int m = 0; m < 4; ++m)
#pragma unroll
      for (int n = 0; n < 2; ++n) {
        acc[m][2 + n] = mfma16(a[m][0], b[2 + n][0], acc[m][2 + n]);
        acc[m][2 + n] = mfma16(a[m][1], b[2 + n][1], acc[m][2 + n]);
      }
    __builtin_amdgcn_s_setprio(0);
    __builtin_amdgcn_s_barrier();

    // ---- P7: read A4-7, MFMA Q(m4-7, n0-1) ----
#pragma unroll
    for (int m = 0; m < 4; ++m) { a[m][0] = ldA(1, 4 + m, 0); a[m][1] = ldA(1, 4 + m, 1); }
    stage(W, tn, t3k, 0, Bs + 16384);     // (t+3).B0
    __builtin_amdgcn_s_barrier();
    asm volatile("s_waitcnt lgkmcnt(0)" ::: "memory");
    __builtin_amdgcn_s_setprio(1);
#pragma unroll
    for (int m = 0; m < 4; ++m)
#pragma unroll
      for (int n = 0; n < 2; ++n) {
        acc[4 + m][n] = mfma16(a[m][0], b[n][0], acc[4 + m][n]);
        acc[4 + m][n] = mfma16(a[m][1], b[n][1], acc[4 + m][n]);
      }
    __builtin_amdgcn_s_setprio(0);
    __builtin_amdgcn_s_barrier();

    // ---- P8: no reads, MFMA Q(m4-7, n2-3); vmcnt guard for tile t+2 ----
    stage(A, tm, t3k, 0, As + 16384);     // (t+3).A0
    asm volatile("s_waitcnt vmcnt(4)" ::: "memory");
    __builtin_amdgcn_s_barrier();
    __builtin_amdgcn_s_setprio(1);
#pragma unroll
    for (int m = 0; m < 4; ++m)
#pragma unroll
      for (int n = 0; n < 2; ++n) {
        acc[4 + m][2 + n] = mfma16(a[m][0], b[2 + n][0], acc[4 + m][2 + n]);
        acc[4 + m][2 + n] = mfma16(a[m][1], b[2 + n][1], acc[4 + m][2 + n]);
      }
    __builtin_amdgcn_s_setprio(0);
    __builtin_amdgcn_s_barrier();
  }
  asm volatile("s_waitcnt vmcnt(0)" ::: "memory");  // drain redundant tail loads
  __builtin_amdgcn_s_barrier();   // ALL waves drained -> LDS reusable in epilogue

  if constexpr (MODE == 0) {
    u16* outp = outb + (size_t)blockIdx.y * 4096 * N;
#pragma unroll
    for (int m = 0; m < 8; ++m)
#pragma unroll
      for (int n = 0; n < 4; ++n) {
        int col = tn + wn * 64 + n * 16 + lrow;
        float bv = (SPLIT == 1 || blockIdx.y == 0) ? bias[col] : 0.f;
#pragma unroll
        for (int r = 0; r < 4; ++r) {
          int row = tm + wm * 128 + m * 16 + lq * 4 + r;
          outp[(size_t)row * N + col] = f2bf(acc[m][n][r] + bv);
        }
      }
  } else if constexpr (MODE == 1) {
#pragma unroll
    for (int m = 0; m < 8; ++m)
#pragma unroll
      for (int n = 0; n < 4; ++n) {
        int col = tn + wn * 64 + n * 16 + lrow;
        float bv = bias[col];
#pragma unroll
        for (int r = 0; r < 4; ++r) {
          int row = tm + wm * 128 + m * 16 + lq * 4 + r;
          outb[(size_t)row * N + col] = f2bf(fmaxf(acc[m][n][r] + bv, 0.f));
        }
      }
  } else {
    const int type = tn >> 10;                  // 0=q, 1=k, 2=v (block-uniform)
    if (type < 2) {
      u16* dst = (type == 0) ? qo : ko;
      const float scale = (type == 0) ? 0.1803368801f : 1.f;  // 1/8*log2e
#pragma unroll
      for (int n = 0; n < 4; ++n) {
        int idx = (tn & 1023) + wn * 64 + n * 16 + lrow;
        int hh = idx >> 6, c = idx & 63;
        float bv = bias[hh * 192 + type * 64 + c];
#pragma unroll
        for (int m = 0; m < 8; ++m) {
#pragma unroll
          for (int r = 0; r < 4; ++r) {
            int row = tm + wm * 128 + m * 16 + lq * 4 + r;
            int bb = row >> 11, s = row & 2047;
            dst[(((size_t)(bb * 16 + hh) * 2048 + s) << 6) + c] =
                f2bf((acc[m][n][r] + bv) * scale);
          }
        }
      }
    } else {
      // V: coalesced write via per-wave LDS transpose. Per (m-pair p, n):
      // transpose a 16-idx x 32-s tile in wave-private LDS so each store
      // instruction covers full 64B lines of vto's [bh][c][s] pages.
      u16* T = lds + wave * 640;            // [16 idx][40 s] u16 (pad 32->40)
      const int bb = tm >> 11;
      const int s_base = (tm & 2047) + wm * 128;
      const int idxl = lane & 15, sg = lane >> 4;
      const int idx2 = (tn & 1023) + wn * 64 + idxl;   // + n*16 added in loop
#pragma unroll
      for (int p = 0; p < 4; ++p) {
#pragma unroll
        for (int n = 0; n < 4; ++n) {
          int idx = (tn & 1023) + wn * 64 + n * 16 + lrow;
          int hh = idx >> 6, c = idx & 63;
          float bv = bias[hh * 192 + 128 + c];
          ushort4 lo, hi;
          lo.x = f2bf(acc[2 * p][n][0] + bv);
          lo.y = f2bf(acc[2 * p][n][1] + bv);
          lo.z = f2bf(acc[2 * p][n][2] + bv);
          lo.w = f2bf(acc[2 * p][n][3] + bv);
          hi.x = f2bf(acc[2 * p + 1][n][0] + bv);
          hi.y = f2bf(acc[2 * p + 1][n][1] + bv);
          hi.z = f2bf(acc[2 * p + 1][n][2] + bv);
          hi.w = f2bf(acc[2 * p + 1][n][3] + bv);
          *(ushort4*)(T + lrow * 40 + lq * 4) = lo;        // s_local = lq*4+r
          *(ushort4*)(T + lrow * 40 + 16 + lq * 4) = hi;   // s_local+16
          asm volatile("s_waitcnt lgkmcnt(0)" ::: "memory");
          int i2 = idx2 + n * 16;
          int hh2 = i2 >> 6, c2 = i2 & 63;
          uint4 v = *(const uint4*)(T + idxl * 40 + sg * 8);
          *(uint4*)(vto + (((size_t)(bb * 16 + hh2) * 64 + c2) << 11)
                        + s_base + p * 32 + sg * 8) = v;
          asm volatile("s_waitcnt lgkmcnt(0)" ::: "memory");  // reads done before next writes
        }
      }
    }
  }
}

// ---------------- Flash attention, 2-way KV-split, 2 Q-frags per wave ------
// R12-PROVEN form (52.9us, VGPR 100): per-half QK+exp (long sacc[8] chain,
// kf re-read per half) + PV fused across halves (vb read once), KVBLK=128,
// double-buffered staging. DO NOT restructure: R4 full-fuse (-6.6us), R10
// QK-dedup (-6.5us), R13 KVBLK=64/4-way split (-5.6us) ALL regressed.
// attn is at its structural floor for this design.
__global__ __launch_bounds__(512)
void attn_kernel(const u16* __restrict__ Q, const u16* __restrict__ K,
                 const u16* __restrict__ Vt,
                 u16* __restrict__ o_part, float* __restrict__ l_part) {
  extern __shared__ u16 smem[];
  u16* Ks = smem;            // [2][128][64], chunk-swizzled
  u16* Vs = smem + 16384;    // [2][64][128], chunk-swizzled
  const int tid = threadIdx.x;
  const int lane = tid & 63;
  const int wave = tid >> 6;      // 0..7
  const int wq = wave & 3;        // staging wave-within-role
  const int role = wave >> 2;     // 0: stage K, 1: stage Vt
  const int lrow = lane & 15;
  const int q = lane >> 4;
  const int bh = blockIdx.x & 31;        // XCD-affine
  const int qb = (blockIdx.x >> 5) & 7;  // 256 q-rows per block
  const int kvh = blockIdx.x >> 8;       // which key half
  const u16* Qp = Q + ((size_t)bh * 2048 + qb * 256) * 64;
  const u16* Kp = K + (size_t)bh * 2048 * 64;
  const u16* Vp = Vt + (size_t)bh * 64 * 2048;

  // two Q fragments per wave: rows wave*16 and 128 + wave*16
  bf16x8 qf[2][2];
#pragma unroll
  for (int h2 = 0; h2 < 2; ++h2)
#pragma unroll
    for (int kk = 0; kk < 2; ++kk)
      qf[h2][kk] = *(const bf16x8*)(Qp + (h2 * 128 + wave * 16 + lrow) * 64 +
                                    kk * 32 + q * 8);

  const s16x4 ones = {(short)0x3F80, (short)0x3F80, (short)0x3F80, (short)0x3F80};
  f32x4 oacc[2][4] = {};
  f32x4 lacc[2] = {};

  auto stage = [&](int kb, int buf) {
    if (role == 0) {
      // waves 0-3 stage K tile [128 keys][64 hd]: 1024 chunks
#pragma unroll
      for (int t = 0; t < 4; ++t) {
        int c = wq * 256 + t * 64 + lane;
        int row = c >> 3, sc = c & 7;
        int cc = sc ^ (row & 7);
        async16(Kp + (size_t)(kb * 128 + row) * 64 + cc * 8,
                Ks + buf * 8192 + (size_t)(wq * 256 + t * 64) * 8);
      }
    } else {
      // waves 4-7 stage Vt tile [64 hd][128 keys]: 1024 chunks
#pragma unroll
      for (int t = 0; t < 4; ++t) {
        int c = wq * 256 + t * 64 + lane;
        int row = c >> 4, sc = c & 15;
        int cc = sc ^ (row & 7);
        async16(Vp + (size_t)row * 2048 + kb * 128 + cc * 8,
                Vs + buf * 8192 + (size_t)(wq * 256 + t * 64) * 8);
      }
    }
  };

  const int kb0 = kvh * 8;
  stage(kb0, 0);
  asm volatile("s_waitcnt vmcnt(0)" ::: "memory");
  __builtin_amdgcn_s_barrier();

  for (int i = 0; i < 8; ++i) {
    const int buf = i & 1;
    if (i < 7) stage(kb0 + i + 1, buf ^ 1);   // prefetch next tile
    const u16* Kb = Ks + buf * 8192;
    const u16* Vb = Vs + buf * 8192;

    // ---- QK^T + exp per half (proven structure), keep both halves' P ----
    s16x4 pa2[2][8];
#pragma unroll
    for (int h2 = 0; h2 < 2; ++h2) {
      f32x4 sacc[8] = {};
#pragma unroll
      for (int j = 0; j < 8; ++j) {
#pragma unroll
        for (int kk = 0; kk < 2; ++kk) {
          int row = j * 16 + lrow;
          int sc = (kk * 4 + q) ^ (row & 7);
          bf16x8 kf = *(const bf16x8*)(Kb + row * 64 + sc * 8);
          sacc[j] = mfma16(kf, qf[h2][kk], sacc[j]);
        }
      }
#pragma unroll
      for (int j = 0; j < 8; ++j) {
        float p0 = exp2_fast(sacc[j][0]);
        float p1 = exp2_fast(sacc[j][1]);
        float p2 = exp2_fast(sacc[j][2]);
        float p3 = exp2_fast(sacc[j][3]);
        u32x2 pw;
        pw.x = pk_bf_trunc(p0, p1);
        pw.y = pk_bf_trunc(p2, p3);
        pa2[h2][j] = __builtin_bit_cast(s16x4, pw);
      }
    }

    // ---- PV + denominator, FUSED: each vb read once, feeds both halves ----
#pragma unroll
    for (int j = 0; j < 8; ++j) {
      lacc[0] = mfma_pv(pa2[0][j], ones, lacc[0]);
      lacc[1] = mfma_pv(pa2[1][j], ones, lacc[1]);
#pragma unroll
      for (int jn = 0; jn < 4; ++jn) {
        int row = jn * 16 + lrow;
        int sc = (j * 2 + (q >> 1)) ^ (row & 7);
        s16x4 vb = *(const s16x4*)(Vb + row * 128 + sc * 8 + (q & 1) * 4);
        oacc[0][jn] = mfma_pv(pa2[0][j], vb, oacc[0][jn]);
        oacc[1][jn] = mfma_pv(pa2[1][j], vb, oacc[1][jn]);
      }
    }

    if (i < 7) {
      asm volatile("s_waitcnt vmcnt(0)" ::: "memory");  // prefetch landed
      __builtin_amdgcn_s_barrier();                     // all reads of buf done
    }
  }

  // write bf16 O-partials (pre-division) + fp32 l-partials
  const int b = bh >> 4, h = bh & 15;
  u16* op = o_part + (size_t)kvh * 4096 * 1024;
  float* lp = l_part + kvh * 65536 + bh * 2048;
#pragma unroll
  for (int h2 = 0; h2 < 2; ++h2) {
#pragma unroll
    for (int r = 0; r < 4; ++r) {
      int s = qb * 256 + h2 * 128 + wave * 16 + q * 4 + r;
      if (lrow == 0) lp[s] = lacc[h2][r];
      size_t base = ((size_t)(b * 2048 + s)) * 1024 + h * 64;
#pragma unroll
      for (int jn = 0; jn < 4; ++jn)
        op[base + jn * 16 + lrow] = f2bf(oacc[h2][jn][r]);
    }
  }
}

// ---------------- combine the two KV halves: ctx = (O0+O1)/(l0+l1) --------
__global__ __launch_bounds__(256)
void attn_combine(const u16* __restrict__ o_part, const float* __restrict__ l_part,
                  u16* __restrict__ ctx) {
  const int t = blockIdx.x;            // token: b = t>>11, s = t&2047
  const int tid = threadIdx.x;
  __shared__ float linv[16];
  if (tid < 16) {
    int b = t >> 11, s = t & 2047;
    int bh = b * 16 + tid;
    linv[tid] = 1.f / (l_part[bh * 2048 + s] + l_part[65536 + bh * 2048 + s]);
  }
  __syncthreads();
  size_t base = (size_t)t * 1024;
  ushort4 a = ((const ushort4*)(o_part + base))[tid];
  ushort4 c = ((const ushort4*)(o_part + 4096ull * 1024 + base))[tid];
  float li = linv[tid >> 4];           // head of d = tid*4 (4-aligned, one head)
  ushort4 o;
  o.x = f2bf((bf2f(a.x) + bf2f(c.x)) * li);
  o.y = f2bf((bf2f(a.y) + bf2f(c.y)) * li);
  o.z = f2bf((bf2f(a.z) + bf2f(c.z)) * li);
  o.w = f2bf((bf2f(a.w) + bf2f(c.w)) * li);
  ((ushort4*)(ctx + base))[tid] = o;
}

// ---------------- LayerNorm over D=1024, fused residual + split-K reduce ----
// x = x1 + sum_{p<P} x2[p]  (x2 partials are bf16, M*N apart). Vectorized:
// thread t owns 4 consecutive elements (float4 / ushort4 loads+stores).
template <int P>
__global__ __launch_bounds__(256)
void ln_kernel(const float* __restrict__ x1, const u16* __restrict__ x2,
               const float* __restrict__ g, const float* __restrict__ bb,
               float* __restrict__ outf, u16* __restrict__ outb) {
  const int t = blockIdx.x;
  const int tid = threadIdx.x;
  const int lane = tid & 63, wave = tid >> 6;
  const size_t base = (size_t)t * 1024;
  const size_t pstride = 4096ull * 1024;
  float4 v = ((const float4*)(x1 + base))[tid];
#pragma unroll
  for (int p = 0; p < P; ++p) {
    ushort4 u = ((const ushort4*)(x2 + p * pstride + base))[tid];
    v.x += bf2f(u.x); v.y += bf2f(u.y); v.z += bf2f(u.z); v.w += bf2f(u.w);
  }
  float s = v.x + v.y + v.z + v.w;
  float s2 = v.x * v.x + v.y * v.y + v.z * v.z + v.w * v.w;
#pragma unroll
  for (int d = 1; d < 64; d <<= 1) {
    s += __shfl_xor(s, d);
    s2 += __shfl_xor(s2, d);
  }
  __shared__ float red[8];
  if (lane == 0) { red[wave] = s; red[4 + wave] = s2; }
  __syncthreads();
  s = red[0] + red[1] + red[2] + red[3];
  s2 = red[4] + red[5] + red[6] + red[7];
  float mean = s * (1.f / 1024.f);
  float var = s2 * (1.f / 1024.f) - mean * mean;
  float rstd = rsqrtf(var + 1e-5f);
  float4 gv = ((const float4*)g)[tid];
  float4 bv = ((const float4*)bb)[tid];
  float4 y;
  y.x = (v.x - mean) * rstd * gv.x + bv.x;
  y.y = (v.y - mean) * rstd * gv.y + bv.y;
  y.z = (v.z - mean) * rstd * gv.z + bv.z;
  y.w = (v.w - mean) * rstd * gv.w + bv.w;
  ((float4*)(outf + base))[tid] = y;
  if (outb) {
    ushort4 ob;
    ob.x = f2bf(y.x); ob.y = f2bf(y.y); ob.z = f2bf(y.z); ob.w = f2bf(y.w);
    ((ushort4*)(outb + base))[tid] = ob;
  }
}

// ---------------- launch ----------------
extern "C" void kernel_launch(void* const* d_in, const int* in_sizes, int n_in,
                              void* d_out, int out_size, void* d_ws, size_t ws_size,
                              hipStream_t stream) {
  const float* src    = (const float*)d_in[0];
  const float* qkv_w  = (const float*)d_in[1];
  const float* qkv_b  = (const float*)d_in[2];
  const float* out_w  = (const float*)d_in[3];
  const float* out_b  = (const float*)d_in[4];
  const float* ffn_w1 = (const float*)d_in[5];
  const float* ffn_b1 = (const float*)d_in[6];
  const float* ffn_w2 = (const float*)d_in[7];
  const float* ffn_b2 = (const float*)d_in[8];
  const float* ln1_g  = (const float*)d_in[9];
  const float* ln1_b  = (const float*)d_in[10];
  const float* ln2_g  = (const float*)d_in[11];
  const float* ln2_b  = (const float*)d_in[12];

  char* ws = (char*)d_ws;
  size_t off = 0;
  auto alloc = [&](size_t bytes) -> void* {
    void* p = ws + off;
    off += (bytes + 255) & ~(size_t)255;
    return p;
  };
  u16* wqkv = (u16*)alloc(3072ull * 1024 * 2);
  u16* wout = (u16*)alloc(1024ull * 1024 * 2);
  u16* wf1  = (u16*)alloc(4096ull * 1024 * 2);
  u16* wf2  = (u16*)alloc(1024ull * 4096 * 2);
  u16* srcb = (u16*)alloc(4096ull * 1024 * 2);
  u16* qb_  = (u16*)alloc(32ull * 2048 * 64 * 2);
  u16* kb_  = (u16*)alloc(32ull * 2048 * 64 * 2);
  u16* vtb  = (u16*)alloc(32ull * 64 * 2048 * 2);
  u16* opart = (u16*)alloc(2ull * 4096 * 1024 * 2);  // 2 bf16 O partials
  float* lpart = (float*)alloc(2ull * 65536 * 4);    // 2 fp32 l partials
  u16* ctxb = (u16*)alloc(4096ull * 1024 * 2);
  u16* mha  = (u16*)alloc(2ull * 4096 * 1024 * 2);   // 2 bf16 split-K partials
  float* aggf = (float*)alloc(4096ull * 1024 * 4);
  u16* aggb = (u16*)alloc(4096ull * 1024 * 2);
  u16* hb   = (u16*)alloc(4096ull * 4096 * 2);
  u16* ffnf = (u16*)alloc(4ull * 4096 * 1024 * 2);   // 4 bf16 split-K partials

  // allow dynamic LDS beyond default (once per process)
  static bool attr_done = false;
  if (!attr_done) {
    auto* kq = gemm8p<2, 1>;
    auto* kf = gemm8p<1, 1>;
    auto* k2 = gemm8p<0, 4>;
    hipFuncSetAttribute(reinterpret_cast<const void*>(kq),
                        hipFuncAttributeMaxDynamicSharedMemorySize, 131072);
    hipFuncSetAttribute(reinterpret_cast<const void*>(kf),
                        hipFuncAttributeMaxDynamicSharedMemorySize, 131072);
    hipFuncSetAttribute(reinterpret_cast<const void*>(k2),
                        hipFuncAttributeMaxDynamicSharedMemorySize, 131072);
    hipFuncSetAttribute(reinterpret_cast<const void*>(attn_kernel),
                        hipFuncAttributeMaxDynamicSharedMemorySize, 65536);
    attr_done = true;
  }

  // fused fp32 -> bf16 converts (single launch; qkv_w rows permuted to grouped order)
  cvt_all<<<16384, 256, 0, stream>>>(qkv_w, out_w, ffn_w1, ffn_w2, src,
                                     wqkv, wout, wf1, wf2, srcb);

  // QKV projection + grouped head scatter (q scaled, v transposed): 8-phase 256^2
  gemm8p<2, 1><<<dim3(192, 1), 512, 131072, stream>>>(srcb, wqkv, qkv_b, nullptr,
                                                      qb_, kb_, vtb, 3072, 1024);
  // flash attention, 2-way KV-split, double-buffered staging -> O/l partials
  attn_kernel<<<512, 512, 65536, stream>>>(qb_, kb_, vtb, opart, lpart);
  // combine partials -> ctx [B,S,D] bf16
  attn_combine<<<4096, 256, 0, stream>>>(opart, lpart, ctxb);
  // output projection -> mha bf16 partials (split-K=2: halves partial traffic
  // vs split-4; 512 blocks still cover the GPU at 2 blocks/CU)
  gemm_bt<0, 2><<<dim3(32, 8, 2), 256, 0, stream>>>(ctxb, wout, out_b, mha,
                                                    nullptr, nullptr, nullptr, 4096, 1024, 1024);
  // LN1(src + sum mha partials) -> agg fp32 + bf16
  ln_kernel<2><<<4096, 256, 0, stream>>>(src, mha, ln1_g, ln1_b, aggf, aggb);
  // FFN1 + ReLU -> h bf16: 8-phase 256^2
  gemm8p<1, 1><<<dim3(256, 1), 512, 131072, stream>>>(aggb, wf1, ffn_b1, hb,
                                                      nullptr, nullptr, nullptr, 4096, 1024);
  // FFN2 -> ffn bf16 partials: 8-phase 256^2, split-K=4 (grid 64x4 = 256 blocks)
  gemm8p<0, 4><<<dim3(64, 4), 512, 131072, stream>>>(hb, wf2, ffn_b2, ffnf,
                                                     nullptr, nullptr, nullptr, 1024, 4096);
  // LN2(agg + sum ffn partials) -> d_out fp32
  ln_kernel<4><<<4096, 256, 0, stream>>>(aggf, ffnf, ln2_g, ln2_b, (float*)d_out, nullptr);
}

// Round 15
// 345.262 us; speedup vs baseline: 1.0398x; 1.0002x over previous
//
#include <hip/hip_runtime.h>

// EncoderBlock: B=2, S=2048, D=1024, H=16, HD=64, F=4096, M=B*S=4096 tokens.

typedef unsigned short u16;
typedef unsigned int u32;
typedef __attribute__((ext_vector_type(8))) __bf16 bf16x8;
typedef __attribute__((ext_vector_type(4))) float f32x4;
typedef __attribute__((ext_vector_type(4))) short s16x4;
typedef __attribute__((ext_vector_type(2))) u32 u32x2;

__device__ __forceinline__ u16 f2bf(float f) {
  u32 u = __float_as_uint(f);
  u += 0x7fffu + ((u >> 16) & 1u);   // RNE
  return (u16)(u >> 16);
}

__device__ __forceinline__ float bf2f(u16 h) {
  return __uint_as_float((u32)h << 16);
}

__device__ __forceinline__ u32 pk_bf_trunc(float a, float b) {
  return (__float_as_uint(a) >> 16) | (__float_as_uint(b) & 0xffff0000u);
}

// Schraudolph-style exp2: 2 full-rate VALU ops vs quarter-rate v_exp_f32.
__device__ __forceinline__ float exp2_fast(float x) {
  float t = __builtin_fmaf(x, 8388608.0f, 1064992506.0f);
  return __int_as_float((int)t);
}

__device__ __forceinline__ void async16(const void* g, void* l) {
  __builtin_amdgcn_global_load_lds((__attribute__((address_space(1))) void*)g,
                                   (__attribute__((address_space(3))) void*)l,
                                   16, 0, 0);
}

__device__ __forceinline__ f32x4 mfma16(bf16x8 a, bf16x8 b, f32x4 c) {
  return __builtin_amdgcn_mfma_f32_16x16x32_bf16(a, b, c, 0, 0, 0);
}

__device__ __forceinline__ f32x4 mfma_pv(s16x4 a, s16x4 b, f32x4 c) {
#if __has_builtin(__builtin_amdgcn_mfma_f32_16x16x16bf16_1k)
  return __builtin_amdgcn_mfma_f32_16x16x16bf16_1k(a, b, c, 0, 0, 0);
#else
  f32x4 d;
  asm("v_mfma_f32_16x16x16_bf16 %0, %1, %2, %3" : "=v"(d) : "v"(a), "v"(b), "v"(c));
  return d;
#endif
}

// ------- fused fp32 -> bf16 convert for all 5 tensors (1 launch) -------
// regions (1024-elem blocks): qkv_w 3072 | out_w 1024 | f1 4096 | f2 4096 | src 4096
// qkv_w rows are PERMUTED on write into grouped order [q 1024 | k 1024 | v 1024].
__global__ __launch_bounds__(256)
void cvt_all(const float* __restrict__ qkv_w, const float* __restrict__ out_w,
             const float* __restrict__ f1, const float* __restrict__ f2,
             const float* __restrict__ src,
             u16* __restrict__ o_qkv, u16* __restrict__ o_out,
             u16* __restrict__ o_f1, u16* __restrict__ o_f2,
             u16* __restrict__ o_src) {
  int b = blockIdx.x;
  const float* in;
  u16* out;
  int lb, ob;
  if (b < 3072) {
    int h = b / 192, c = b - h * 192;
    ob = (c < 64) ? h * 64 + c : (c < 128) ? 1024 + h * 64 + (c - 64)
                                           : 2048 + h * 64 + (c - 128);
    in = qkv_w; out = o_qkv; lb = b;
  }
  else if (b < 4096)  { in = out_w; out = o_out; lb = b - 3072;  ob = lb; }
  else if (b < 8192)  { in = f1;    out = o_f1;  lb = b - 4096;  ob = lb; }
  else if (b < 12288) { in = f2;    out = o_f2;  lb = b - 8192;  ob = lb; }
  else                { in = src;   out = o_src; lb = b - 12288; ob = lb; }
  int i = lb * 256 + threadIdx.x;
  int o = ob * 256 + threadIdx.x;
  float4 v = ((const float4*)in)[i];
  ushort4 ov;
  ov.x = f2bf(v.x); ov.y = f2bf(v.y); ov.z = f2bf(v.z); ov.w = f2bf(v.w);
  ((ushort4*)out)[o] = ov;
}

// ---------------- GEMM (legacy 128x128, 2-barrier): C[M,N] = A @ W^T + bias --
// Kept for out-proj (split-K, small FLOP count).
// MODE 0: bf16 PARTIAL out per z-slice. MODE 1: bf16 out with ReLU.
template <int MODE, int SPLIT>
__global__ __launch_bounds__(256)
void gemm_bt(const u16* __restrict__ A, const u16* __restrict__ W,
             const float* __restrict__ bias,
             u16* __restrict__ outb,
             u16* __restrict__ qo, u16* __restrict__ ko, u16* __restrict__ vto,
             int M, int N, int K) {
  __shared__ u16 As[128 * 64];
  __shared__ u16 Bs[128 * 64];
  const int lane = threadIdx.x & 63;
  const int wave = threadIdx.x >> 6;
  const int lrow = lane & 15;
  const int lq = lane >> 4;
  const int tm = blockIdx.x * 128;
  const int tn = blockIdx.y * 128;
  const int wm = (wave >> 1) * 64;
  const int wn = (wave & 1) * 64;
  const int kc = K / SPLIT;
  const int kbeg = blockIdx.z * kc;
  f32x4 acc[4][4] = {};

  for (int k0 = kbeg; k0 < kbeg + kc; k0 += 64) {
#pragma unroll
    for (int c = 0; c < 4; ++c) {
      int chunk = wave * 256 + c * 64 + lane;
      int row = chunk >> 3;
      int sc = chunk & 7;
      int cc = sc ^ (row & 7);                   // swizzled source chunk
      u16* la = As + (size_t)(wave * 256 + c * 64) * 8;  // wave-uniform base
      u16* lb = Bs + (size_t)(wave * 256 + c * 64) * 8;
      async16(A + (size_t)(tm + row) * K + (k0 + cc * 8), la);
      async16(W + (size_t)(tn + row) * K + (k0 + cc * 8), lb);
    }
    __syncthreads();
#pragma unroll
    for (int h = 0; h < 2; ++h) {   // two 32-k halves per staged tile
      bf16x8 a_frag[4], b_frag[4];
#pragma unroll
      for (int i = 0; i < 4; ++i) {
        int row = wm + i * 16 + lrow;
        int sc = (h * 4 + lq) ^ (row & 7);
        a_frag[i] = *(const bf16x8*)(As + row * 64 + sc * 8);
      }
#pragma unroll
      for (int j = 0; j < 4; ++j) {
        int row = wn + j * 16 + lrow;
        int sc = (h * 4 + lq) ^ (row & 7);
        b_frag[j] = *(const bf16x8*)(Bs + row * 64 + sc * 8);
      }
#pragma unroll
      for (int i = 0; i < 4; ++i)
#pragma unroll
        for (int j = 0; j < 4; ++j)
          acc[i][j] = mfma16(a_frag[i], b_frag[j], acc[i][j]);
    }
    __syncthreads();
  }

  u16* outp = outb;
  if constexpr (MODE == 0) outp += (size_t)blockIdx.z * M * N;

#pragma unroll
  for (int i = 0; i < 4; ++i) {
#pragma unroll
    for (int j = 0; j < 4; ++j) {
      int col = tn + wn + j * 16 + lrow;
      float bv = (SPLIT == 1 || blockIdx.z == 0) ? bias[col] : 0.f;
#pragma unroll
      for (int r = 0; r < 4; ++r) {
        int row = tm + wm + i * 16 + lq * 4 + r;
        float v = acc[i][j][r] + bv;
        if constexpr (MODE == 0) {
          outp[(size_t)row * N + col] = f2bf(v);   // bf16 partial
        } else {
          outp[(size_t)row * N + col] = f2bf(fmaxf(v, 0.f));
        }
      }
    }
  }
}

// ---------------- GEMM 256x256, 8-phase counted-vmcnt schedule (T2+T3+T4+T5) --
// M=4096 fixed; per-z K chunk = 1024 fixed (16 k-tiles); Kfull is the row
// stride (Kfull = 1024*SPLIT). blockIdx.y = z (split-K slice). 512 threads =
// 8 waves (2M x 4N); per-wave C = 128x64 (8x4 16x16 frags). BK=64,
// double-buffered 128 KiB LDS (dynamic): As[2][256][64] | Bs[2][256][64],
// chunk-XOR swizzle. Schedule/safety/readiness comments as verified in R6.
// XCD-RECTANGLE swizzle: per XCD a 4tm x (NTN/2)tn rectangle so the per-XCD
// L2 footprint is A 2MB + W <=3-4MB (R13 counters: QKV FETCH 42.6->25.1MB).
// xcd = wg&7, loc = wg>>3: tm_idx = (xcd&3)*4 + (loc&3),
// tn_idx = (xcd>>2)*(NTN/2) + (loc>>2). Bijective (grids 192/256/64).
// MODE 0: bf16 partial out per z. MODE 1: ReLU bf16 out. MODE 2: QKV scatter
// (V path writes via per-wave LDS transpose for full-line coalescing).
template <int MODE, int SPLIT>
__global__ __launch_bounds__(512, 2)
void gemm8p(const u16* __restrict__ A, const u16* __restrict__ W,
            const float* __restrict__ bias, u16* __restrict__ outb,
            u16* __restrict__ qo, u16* __restrict__ ko, u16* __restrict__ vto,
            int N, int Kfull) {
  extern __shared__ u16 lds[];
  constexpr int NTK = 16;         // k-tiles per z-slice (K chunk = 1024)
  constexpr int NG = NTK / 2;     // 8 groups
  u16* As = lds;                  // [2][256][64]
  u16* Bs = lds + 32768;
  const int tid = threadIdx.x;
  const int lane = tid & 63;
  const int wave = tid >> 6;
  const int lrow = lane & 15;
  const int lq = lane >> 4;
  const int wm = wave >> 2;       // 0..1
  const int wn = wave & 3;        // 0..3
  const int kbeg = blockIdx.y * 1024;   // z-slice K offset

  // XCD-rectangle swizzle (bijective; gridDim.x = 16*NTN, NTN even)
  const int wg = blockIdx.x;
  const int ntn2 = gridDim.x >> 5;      // NTN/2
  const int xcd = wg & 7, loc = wg >> 3;
  const int tm = ((xcd & 3) * 4 + (loc & 3)) * 256;
  const int tn = ((xcd >> 2) * ntn2 + (loc >> 2)) * 256;

  auto stage = [&](const u16* __restrict__ T, int trow0, int kt, int rbase,
                   u16* base) {
#pragma unroll
    for (int it = 0; it < 2; ++it) {
      int c = it * 512 + tid;
      int row = c >> 3, sc = c & 7, cc = sc ^ (row & 7);
      async16(T + (size_t)(trow0 + rbase + row) * Kfull + kbeg + kt * 64 + cc * 8,
              base + rbase * 64 + (it * 512 + wave * 64) * 8);
    }
  };
  auto ldA = [&](int buf, int m, int h) {
    int row = wm * 128 + m * 16 + lrow;
    int sc = (h * 4 + lq) ^ (row & 7);
    return *(const bf16x8*)(As + buf * 16384 + row * 64 + sc * 8);
  };
  auto ldB = [&](int buf, int n, int h) {
    int row = wn * 64 + n * 16 + lrow;
    int sc = (h * 4 + lq) ^ (row & 7);
    return *(const bf16x8*)(Bs + buf * 16384 + row * 64 + sc * 8);
  };

  f32x4 acc[8][4] = {};
  bf16x8 a[4][2], b[4][2];

  // prologue: t0 fully + t1.B0 + t1.A0 (order matters for the vmcnt account)
  stage(A, tm, 0, 0, As);
  stage(A, tm, 0, 128, As);
  stage(W, tn, 0, 0, Bs);
  stage(W, tn, 0, 128, Bs);
  stage(W, tn, 1, 0, Bs + 16384);
  stage(A, tm, 1, 0, As + 16384);
  asm volatile("s_waitcnt vmcnt(4)" ::: "memory");
  __builtin_amdgcn_s_barrier();

  for (int g = 0; g < NG; ++g) {
    const int t = 2 * g;
    const int t1k = t + 1;                            // always < NTK
    const int t2k = (t + 2 < NTK) ? t + 2 : NTK - 1;  // clamp (last group)
    const int t3k = (t + 3 < NTK) ? t + 3 : NTK - 1;

    // ---- P1: tile t (buf0) : read A0-3 + B0-1, MFMA Q(m0-3, n0-1) ----
#pragma unroll
    for (int m = 0; m < 4; ++m) { a[m][0] = ldA(0, m, 0); a[m][1] = ldA(0, m, 1); }
#pragma unroll
    for (int n = 0; n < 2; ++n) { b[n][0] = ldB(0, n, 0); b[n][1] = ldB(0, n, 1); }
    stage(A, tm, t1k, 128, As + 16384);   // (t+1).A1
    __builtin_amdgcn_s_barrier();
    asm volatile("s_waitcnt lgkmcnt(0)" ::: "memory");
    __builtin_amdgcn_s_setprio(1);
#pragma unroll
    for (int m = 0; m < 4; ++m)
#pragma unroll
      for (int n = 0; n < 2; ++n) {
        acc[m][n] = mfma16(a[m][0], b[n][0], acc[m][n]);
        acc[m][n] = mfma16(a[m][1], b[n][1], acc[m][n]);
      }
    __builtin_amdgcn_s_setprio(0);
    __builtin_amdgcn_s_barrier();

    // ---- P2: read B2-3, MFMA Q(m0-3, n2-3) ----
#pragma unroll
    for (int n = 0; n < 2; ++n) { b[2 + n][0] = ldB(0, 2 + n, 0); b[2 + n][1] = ldB(0, 2 + n, 1); }
    stage(W, tn, t1k, 128, Bs + 16384);   // (t+1).B1
    __builtin_amdgcn_s_barrier();
    asm volatile("s_waitcnt lgkmcnt(0)" ::: "memory");
    __builtin_amdgcn_s_setprio(1);
#pragma unroll
    for (int m = 0; m < 4; ++m)
#pragma unroll
      for (int n = 0; n < 2; ++n) {
        acc[m][2 + n] = mfma16(a[m][0], b[2 + n][0], acc[m][2 + n]);
        acc[m][2 + n] = mfma16(a[m][1], b[2 + n][1], acc[m][2 + n]);
      }
    __builtin_amdgcn_s_setprio(0);
    __builtin_amdgcn_s_barrier();

    // ---- P3: read A4-7 (reuse regs), MFMA Q(m4-7, n0-1) ----
#pragma unroll
    for (int m = 0; m < 4; ++m) { a[m][0] = ldA(0, 4 + m, 0); a[m][1] = ldA(0, 4 + m, 1); }
    stage(W, tn, t2k, 0, Bs);             // (t+2).B0
    __builtin_amdgcn_s_barrier();
    asm volatile("s_waitcnt lgkmcnt(0)" ::: "memory");
    __builtin_amdgcn_s_setprio(1);
#pragma unroll
    for (int m = 0; m < 4; ++m)
#pragma unroll
      for (int n = 0; n < 2; ++n) {
        acc[4 + m][n] = mfma16(a[m][0], b[n][0], acc[4 + m][n]);
        acc[4 + m][n] = mfma16(a[m][1], b[n][1], acc[4 + m][n]);
      }
    __builtin_amdgcn_s_setprio(0);
    __builtin_amdgcn_s_barrier();

    // ---- P4: no reads, MFMA Q(m4-7, n2-3); vmcnt guard for tile t+1 ----
    stage(A, tm, t2k, 0, As);             // (t+2).A0
    asm volatile("s_waitcnt vmcnt(4)" ::: "memory");
    __builtin_amdgcn_s_barrier();
    __builtin_amdgcn_s_setprio(1);
#pragma unroll
    for (int m = 0; m < 4; ++m)
#pragma unroll
      for (int n = 0; n < 2; ++n) {
        acc[4 + m][2 + n] = mfma16(a[m][0], b[2 + n][0], acc[4 + m][2 + n]);
        acc[4 + m][2 + n] = mfma16(a[m][1], b[2 + n][1], acc[4 + m][2 + n]);
      }
    __builtin_amdgcn_s_setprio(0);
    __builtin_amdgcn_s_barrier();

    // ---- P5: tile t+1 (buf1) : read A0-3 + B0-1, MFMA Q(m0-3, n0-1) ----
#pragma unroll
    for (int m = 0; m < 4; ++m) { a[m][0] = ldA(1, m, 0); a[m][1] = ldA(1, m, 1); }
#pragma unroll
    for (int n = 0; n < 2; ++n) { b[n][0] = ldB(1, n, 0); b[n][1] = ldB(1, n, 1); }
    stage(A, tm, t2k, 128, As);           // (t+2).A1
    __builtin_amdgcn_s_barrier();
    asm volatile("s_waitcnt lgkmcnt(0)" ::: "memory");
    __builtin_amdgcn_s_setprio(1);
#pragma unroll
    for (int m = 0; m < 4; ++m)
#pragma unroll
      for (int n = 0; n < 2; ++n) {
        acc[m][n] = mfma16(a[m][0], b[n][0], acc[m][n]);
        acc[m][n] = mfma16(a[m][1], b[n][1], acc[m][n]);
      }
    __builtin_amdgcn_s_setprio(0);
    __builtin_amdgcn_s_barrier();

    // ---- P6: read B2-3, MFMA Q(m0-3, n2-3) ----
#pragma unroll
    for (int n = 0; n < 2; ++n) { b[2 + n][0] = ldB(1, 2 + n, 0); b[2 + n][1] = ldB(1, 2 + n, 1); }
    stage(W, tn, t2k, 128, Bs);           // (t+2).B1
    __builtin_amdgcn_s_barrier();
    asm volatile("s_waitcnt lgkmcnt(0)" ::: "memory");
    __builtin_amdgcn_s_setprio(1);
#pragma unroll
    for (int m = 0; m < 4; ++m)
#pragma unroll
      for (int n = 0; n < 2; ++n) {
        acc[m][2 + n] = mfma16(a[m][0], b[2 + n][0], acc[m][2 + n]);
        acc[m][2 + n] = mfma16(a[m][1], b[2 + n][1], acc[m][2 + n]);
      }
    __builtin_amdgcn_s_setprio(0);
    __builtin_amdgcn_s_barrier();

    // ---- P7: read A4-7, MFMA Q(m4-7, n0-1) ----
#pragma unroll
    for (int m = 0; m < 4; ++m) { a[m][0] = ldA(1, 4 + m, 0); a[m][1] = ldA(1, 4 + m, 1); }
    stage(W, tn, t3k, 0, Bs + 16384);     // (t+3).B0
    __builtin_amdgcn_s_barrier();
    asm volatile("s_waitcnt lgkmcnt(0)" ::: "memory");
    __builtin_amdgcn_s_setprio(1);
#pragma unroll
    for (int m = 0; m < 4; ++m)
#pragma unroll
      for (int n = 0; n < 2; ++n) {
        acc[4 + m][n] = mfma16(a[m][0], b[n][0], acc[4 + m][n]);
        acc[4 + m][n] = mfma16(a[m][1], b[n][1], acc[4 + m][n]);
      }
    __builtin_amdgcn_s_setprio(0);
    __builtin_amdgcn_s_barrier();

    // ---- P8: no reads, MFMA Q(m4-7, n2-3); vmcnt guard for tile t+2 ----
    stage(A, tm, t3k, 0, As + 16384);     // (t+3).A0
    asm volatile("s_waitcnt vmcnt(4)" ::: "memory");
    __builtin_amdgcn_s_barrier();
    __builtin_amdgcn_s_setprio(1);
#pragma unroll
    for (int m = 0; m < 4; ++m)
#pragma unroll
      for (int n = 0; n < 2; ++n) {
        acc[4 + m][2 + n] = mfma16(a[m][0], b[2 + n][0], acc[4 + m][2 + n]);
        acc[4 + m][2 + n] = mfma16(a[m][1], b[2 + n][1], acc[4 + m][2 + n]);
      }
    __builtin_amdgcn_s_setprio(0);
    __builtin_amdgcn_s_barrier();
  }
  asm volatile("s_waitcnt vmcnt(0)" ::: "memory");  // drain redundant tail loads
  __builtin_amdgcn_s_barrier();   // ALL waves drained -> LDS reusable in epilogue

  if constexpr (MODE == 0) {
    u16* outp = outb + (size_t)blockIdx.y * 4096 * N;
#pragma unroll
    for (int m = 0; m < 8; ++m)
#pragma unroll
      for (int n = 0; n < 4; ++n) {
        int col = tn + wn * 64 + n * 16 + lrow;
        float bv = (SPLIT == 1 || blockIdx.y == 0) ? bias[col] : 0.f;
#pragma unroll
        for (int r = 0; r < 4; ++r) {
          int row = tm + wm * 128 + m * 16 + lq * 4 + r;
          outp[(size_t)row * N + col] = f2bf(acc[m][n][r] + bv);
        }
      }
  } else if constexpr (MODE == 1) {
#pragma unroll
    for (int m = 0; m < 8; ++m)
#pragma unroll
      for (int n = 0; n < 4; ++n) {
        int col = tn + wn * 64 + n * 16 + lrow;
        float bv = bias[col];
#pragma unroll
        for (int r = 0; r < 4; ++r) {
          int row = tm + wm * 128 + m * 16 + lq * 4 + r;
          outb[(size_t)row * N + col] = f2bf(fmaxf(acc[m][n][r] + bv, 0.f));
        }
      }
  } else {
    const int type = tn >> 10;                  // 0=q, 1=k, 2=v (block-uniform)
    if (type < 2) {
      u16* dst = (type == 0) ? qo : ko;
      const float scale = (type == 0) ? 0.1803368801f : 1.f;  // 1/8*log2e
#pragma unroll
      for (int n = 0; n < 4; ++n) {
        int idx = (tn & 1023) + wn * 64 + n * 16 + lrow;
        int hh = idx >> 6, c = idx & 63;
        float bv = bias[hh * 192 + type * 64 + c];
#pragma unroll
        for (int m = 0; m < 8; ++m) {
#pragma unroll
          for (int r = 0; r < 4; ++r) {
            int row = tm + wm * 128 + m * 16 + lq * 4 + r;
            int bb = row >> 11, s = row & 2047;
            dst[(((size_t)(bb * 16 + hh) * 2048 + s) << 6) + c] =
                f2bf((acc[m][n][r] + bv) * scale);
          }
        }
      }
    } else {
      // V: coalesced write via per-wave LDS transpose. Per (m-pair p, n):
      // transpose a 16-idx x 32-s tile in wave-private LDS so each store
      // instruction covers full 64B lines of vto's [bh][c][s] pages.
      u16* T = lds + wave * 640;            // [16 idx][40 s] u16 (pad 32->40)
      const int bb = tm >> 11;
      const int s_base = (tm & 2047) + wm * 128;
      const int idxl = lane & 15, sg = lane >> 4;
      const int idx2 = (tn & 1023) + wn * 64 + idxl;   // + n*16 added in loop
#pragma unroll
      for (int p = 0; p < 4; ++p) {
#pragma unroll
        for (int n = 0; n < 4; ++n) {
          int idx = (tn & 1023) + wn * 64 + n * 16 + lrow;
          int hh = idx >> 6, c = idx & 63;
          float bv = bias[hh * 192 + 128 + c];
          ushort4 lo, hi;
          lo.x = f2bf(acc[2 * p][n][0] + bv);
          lo.y = f2bf(acc[2 * p][n][1] + bv);
          lo.z = f2bf(acc[2 * p][n][2] + bv);
          lo.w = f2bf(acc[2 * p][n][3] + bv);
          hi.x = f2bf(acc[2 * p + 1][n][0] + bv);
          hi.y = f2bf(acc[2 * p + 1][n][1] + bv);
          hi.z = f2bf(acc[2 * p + 1][n][2] + bv);
          hi.w = f2bf(acc[2 * p + 1][n][3] + bv);
          *(ushort4*)(T + lrow * 40 + lq * 4) = lo;        // s_local = lq*4+r
          *(ushort4*)(T + lrow * 40 + 16 + lq * 4) = hi;   // s_local+16
          asm volatile("s_waitcnt lgkmcnt(0)" ::: "memory");
          int i2 = idx2 + n * 16;
          int hh2 = i2 >> 6, c2 = i2 & 63;
          uint4 v = *(const uint4*)(T + idxl * 40 + sg * 8);
          *(uint4*)(vto + (((size_t)(bb * 16 + hh2) * 64 + c2) << 11)
                        + s_base + p * 32 + sg * 8) = v;
          asm volatile("s_waitcnt lgkmcnt(0)" ::: "memory");  // reads done before next writes
        }
      }
    }
  }
}

// ---------------- Flash attention, 2-way KV-split, 2 Q-frags per wave ------
// R12-PROVEN form (52.9us, VGPR 100): per-half QK+exp (long sacc[8] chain,
// kf re-read per half) + PV fused across halves (vb read once), KVBLK=128,
// double-buffered staging. DO NOT restructure: R4 full-fuse (-6.6us), R10
// QK-dedup (-6.5us), R13 KVBLK=64/4-way split (-5.6us) ALL regressed.
// attn is at its structural floor for this design.
__global__ __launch_bounds__(512)
void attn_kernel(const u16* __restrict__ Q, const u16* __restrict__ K,
                 const u16* __restrict__ Vt,
                 u16* __restrict__ o_part, float* __restrict__ l_part) {
  extern __shared__ u16 smem[];
  u16* Ks = smem;            // [2][128][64], chunk-swizzled
  u16* Vs = smem + 16384;    // [2][64][128], chunk-swizzled
  const int tid = threadIdx.x;
  const int lane = tid & 63;
  const int wave = tid >> 6;      // 0..7
  const int wq = wave & 3;        // staging wave-within-role
  const int role = wave >> 2;     // 0: stage K, 1: stage Vt
  const int lrow = lane & 15;
  const int q = lane >> 4;
  const int bh = blockIdx.x & 31;        // XCD-affine
  const int qb = (blockIdx.x >> 5) & 7;  // 256 q-rows per block
  const int kvh = blockIdx.x >> 8;       // which key half
  const u16* Qp = Q + ((size_t)bh * 2048 + qb * 256) * 64;
  const u16* Kp = K + (size_t)bh * 2048 * 64;
  const u16* Vp = Vt + (size_t)bh * 64 * 2048;

  // two Q fragments per wave: rows wave*16 and 128 + wave*16
  bf16x8 qf[2][2];
#pragma unroll
  for (int h2 = 0; h2 < 2; ++h2)
#pragma unroll
    for (int kk = 0; kk < 2; ++kk)
      qf[h2][kk] = *(const bf16x8*)(Qp + (h2 * 128 + wave * 16 + lrow) * 64 +
                                    kk * 32 + q * 8);

  const s16x4 ones = {(short)0x3F80, (short)0x3F80, (short)0x3F80, (short)0x3F80};
  f32x4 oacc[2][4] = {};
  f32x4 lacc[2] = {};

  auto stage = [&](int kb, int buf) {
    if (role == 0) {
      // waves 0-3 stage K tile [128 keys][64 hd]: 1024 chunks
#pragma unroll
      for (int t = 0; t < 4; ++t) {
        int c = wq * 256 + t * 64 + lane;
        int row = c >> 3, sc = c & 7;
        int cc = sc ^ (row & 7);
        async16(Kp + (size_t)(kb * 128 + row) * 64 + cc * 8,
                Ks + buf * 8192 + (size_t)(wq * 256 + t * 64) * 8);
      }
    } else {
      // waves 4-7 stage Vt tile [64 hd][128 keys]: 1024 chunks
#pragma unroll
      for (int t = 0; t < 4; ++t) {
        int c = wq * 256 + t * 64 + lane;
        int row = c >> 4, sc = c & 15;
        int cc = sc ^ (row & 7);
        async16(Vp + (size_t)row * 2048 + kb * 128 + cc * 8,
                Vs + buf * 8192 + (size_t)(wq * 256 + t * 64) * 8);
      }
    }
  };

  const int kb0 = kvh * 8;
  stage(kb0, 0);
  asm volatile("s_waitcnt vmcnt(0)" ::: "memory");
  __builtin_amdgcn_s_barrier();

  for (int i = 0; i < 8; ++i) {
    const int buf = i & 1;
    if (i < 7) stage(kb0 + i + 1, buf ^ 1);   // prefetch next tile
    const u16* Kb = Ks + buf * 8192;
    const u16* Vb = Vs + buf * 8192;

    // ---- QK^T + exp per half (proven structure), keep both halves' P ----
    s16x4 pa2[2][8];
#pragma unroll
    for (int h2 = 0; h2 < 2; ++h2) {
      f32x4 sacc[8] = {};
#pragma unroll
      for (int j = 0; j < 8; ++j) {
#pragma unroll
        for (int kk = 0; kk < 2; ++kk) {
          int row = j * 16 + lrow;
          int sc = (kk * 4 + q) ^ (row & 7);
          bf16x8 kf = *(const bf16x8*)(Kb + row * 64 + sc * 8);
          sacc[j] = mfma16(kf, qf[h2][kk], sacc[j]);
        }
      }
#pragma unroll
      for (int j = 0; j < 8; ++j) {
        float p0 = exp2_fast(sacc[j][0]);
        float p1 = exp2_fast(sacc[j][1]);
        float p2 = exp2_fast(sacc[j][2]);
        float p3 = exp2_fast(sacc[j][3]);
        u32x2 pw;
        pw.x = pk_bf_trunc(p0, p1);
        pw.y = pk_bf_trunc(p2, p3);
        pa2[h2][j] = __builtin_bit_cast(s16x4, pw);
      }
    }

    // ---- PV + denominator, FUSED: each vb read once, feeds both halves ----
#pragma unroll
    for (int j = 0; j < 8; ++j) {
      lacc[0] = mfma_pv(pa2[0][j], ones, lacc[0]);
      lacc[1] = mfma_pv(pa2[1][j], ones, lacc[1]);
#pragma unroll
      for (int jn = 0; jn < 4; ++jn) {
        int row = jn * 16 + lrow;
        int sc = (j * 2 + (q >> 1)) ^ (row & 7);
        s16x4 vb = *(const s16x4*)(Vb + row * 128 + sc * 8 + (q & 1) * 4);
        oacc[0][jn] = mfma_pv(pa2[0][j], vb, oacc[0][jn]);
        oacc[1][jn] = mfma_pv(pa2[1][j], vb, oacc[1][jn]);
      }
    }

    if (i < 7) {
      asm volatile("s_waitcnt vmcnt(0)" ::: "memory");  // prefetch landed
      __builtin_amdgcn_s_barrier();                     // all reads of buf done
    }
  }

  // write bf16 O-partials (pre-division) + fp32 l-partials
  const int b = bh >> 4, h = bh & 15;
  u16* op = o_part + (size_t)kvh * 4096 * 1024;
  float* lp = l_part + kvh * 65536 + bh * 2048;
#pragma unroll
  for (int h2 = 0; h2 < 2; ++h2) {
#pragma unroll
    for (int r = 0; r < 4; ++r) {
      int s = qb * 256 + h2 * 128 + wave * 16 + q * 4 + r;
      if (lrow == 0) lp[s] = lacc[h2][r];
      size_t base = ((size_t)(b * 2048 + s)) * 1024 + h * 64;
#pragma unroll
      for (int jn = 0; jn < 4; ++jn)
        op[base + jn * 16 + lrow] = f2bf(oacc[h2][jn][r]);
    }
  }
}

// ---------------- combine the two KV halves: ctx = (O0+O1)/(l0+l1) --------
__global__ __launch_bounds__(256)
void attn_combine(const u16* __restrict__ o_part, const float* __restrict__ l_part,
                  u16* __restrict__ ctx) {
  const int t = blockIdx.x;            // token: b = t>>11, s = t&2047
  const int tid = threadIdx.x;
  __shared__ float linv[16];
  if (tid < 16) {
    int b = t >> 11, s = t & 2047;
    int bh = b * 16 + tid;
    linv[tid] = 1.f / (l_part[bh * 2048 + s] + l_part[65536 + bh * 2048 + s]);
  }
  __syncthreads();
  size_t base = (size_t)t * 1024;
  ushort4 a = ((const ushort4*)(o_part + base))[tid];
  ushort4 c = ((const ushort4*)(o_part + 4096ull * 1024 + base))[tid];
  float li = linv[tid >> 4];           // head of d = tid*4 (4-aligned, one head)
  ushort4 o;
  o.x = f2bf((bf2f(a.x) + bf2f(c.x)) * li);
  o.y = f2bf((bf2f(a.y) + bf2f(c.y)) * li);
  o.z = f2bf((bf2f(a.z) + bf2f(c.z)) * li);
  o.w = f2bf((bf2f(a.w) + bf2f(c.w)) * li);
  ((ushort4*)(ctx + base))[tid] = o;
}

// ---------------- LayerNorm over D=1024, fused residual + split-K reduce ----
// x = x1 + sum_{p<P} x2[p]  (x2 partials are bf16, M*N apart). Vectorized:
// thread t owns 4 consecutive elements (float4 / ushort4 loads+stores).
template <int P>
__global__ __launch_bounds__(256)
void ln_kernel(const float* __restrict__ x1, const u16* __restrict__ x2,
               const float* __restrict__ g, const float* __restrict__ bb,
               float* __restrict__ outf, u16* __restrict__ outb) {
  const int t = blockIdx.x;
  const int tid = threadIdx.x;
  const int lane = tid & 63, wave = tid >> 6;
  const size_t base = (size_t)t * 1024;
  const size_t pstride = 4096ull * 1024;
  float4 v = ((const float4*)(x1 + base))[tid];
#pragma unroll
  for (int p = 0; p < P; ++p) {
    ushort4 u = ((const ushort4*)(x2 + p * pstride + base))[tid];
    v.x += bf2f(u.x); v.y += bf2f(u.y); v.z += bf2f(u.z); v.w += bf2f(u.w);
  }
  float s = v.x + v.y + v.z + v.w;
  float s2 = v.x * v.x + v.y * v.y + v.z * v.z + v.w * v.w;
#pragma unroll
  for (int d = 1; d < 64; d <<= 1) {
    s += __shfl_xor(s, d);
    s2 += __shfl_xor(s2, d);
  }
  __shared__ float red[8];
  if (lane == 0) { red[wave] = s; red[4 + wave] = s2; }
  __syncthreads();
  s = red[0] + red[1] + red[2] + red[3];
  s2 = red[4] + red[5] + red[6] + red[7];
  float mean = s * (1.f / 1024.f);
  float var = s2 * (1.f / 1024.f) - mean * mean;
  float rstd = rsqrtf(var + 1e-5f);
  float4 gv = ((const float4*)g)[tid];
  float4 bv = ((const float4*)bb)[tid];
  float4 y;
  y.x = (v.x - mean) * rstd * gv.x + bv.x;
  y.y = (v.y - mean) * rstd * gv.y + bv.y;
  y.z = (v.z - mean) * rstd * gv.z + bv.z;
  y.w = (v.w - mean) * rstd * gv.w + bv.w;
  ((float4*)(outf + base))[tid] = y;
  if (outb) {
    ushort4 ob;
    ob.x = f2bf(y.x); ob.y = f2bf(y.y); ob.z = f2bf(y.z); ob.w = f2bf(y.w);
    ((ushort4*)(outb + base))[tid] = ob;
  }
}

// ---------------- launch ----------------
extern "C" void kernel_launch(void* const* d_in, const int* in_sizes, int n_in,
                              void* d_out, int out_size, void* d_ws, size_t ws_size,
                              hipStream_t stream) {
  const float* src    = (const float*)d_in[0];
  const float* qkv_w  = (const float*)d_in[1];
  const float* qkv_b  = (const float*)d_in[2];
  const float* out_w  = (const float*)d_in[3];
  const float* out_b  = (const float*)d_in[4];
  const float* ffn_w1 = (const float*)d_in[5];
  const float* ffn_b1 = (const float*)d_in[6];
  const float* ffn_w2 = (const float*)d_in[7];
  const float* ffn_b2 = (const float*)d_in[8];
  const float* ln1_g  = (const float*)d_in[9];
  const float* ln1_b  = (const float*)d_in[10];
  const float* ln2_g  = (const float*)d_in[11];
  const float* ln2_b  = (const float*)d_in[12];

  char* ws = (char*)d_ws;
  size_t off = 0;
  auto alloc = [&](size_t bytes) -> void* {
    void* p = ws + off;
    off += (bytes + 255) & ~(size_t)255;
    return p;
  };
  u16* wqkv = (u16*)alloc(3072ull * 1024 * 2);
  u16* wout = (u16*)alloc(1024ull * 1024 * 2);
  u16* wf1  = (u16*)alloc(4096ull * 1024 * 2);
  u16* wf2  = (u16*)alloc(1024ull * 4096 * 2);
  u16* srcb = (u16*)alloc(4096ull * 1024 * 2);
  u16* qb_  = (u16*)alloc(32ull * 2048 * 64 * 2);
  u16* kb_  = (u16*)alloc(32ull * 2048 * 64 * 2);
  u16* vtb  = (u16*)alloc(32ull * 64 * 2048 * 2);
  u16* opart = (u16*)alloc(2ull * 4096 * 1024 * 2);  // 2 bf16 O partials
  float* lpart = (float*)alloc(2ull * 65536 * 4);    // 2 fp32 l partials
  u16* ctxb = (u16*)alloc(4096ull * 1024 * 2);
  u16* mha  = (u16*)alloc(1ull * 4096 * 1024 * 2);   // 1 bf16 out (split-1)
  float* aggf = (float*)alloc(4096ull * 1024 * 4);
  u16* aggb = (u16*)alloc(4096ull * 1024 * 2);
  u16* hb   = (u16*)alloc(4096ull * 4096 * 2);
  u16* ffnf = (u16*)alloc(4ull * 4096 * 1024 * 2);   // 4 bf16 split-K partials

  // allow dynamic LDS beyond default (once per process)
  static bool attr_done = false;
  if (!attr_done) {
    auto* kq = gemm8p<2, 1>;
    auto* kf = gemm8p<1, 1>;
    auto* k2 = gemm8p<0, 4>;
    hipFuncSetAttribute(reinterpret_cast<const void*>(kq),
                        hipFuncAttributeMaxDynamicSharedMemorySize, 131072);
    hipFuncSetAttribute(reinterpret_cast<const void*>(kf),
                        hipFuncAttributeMaxDynamicSharedMemorySize, 131072);
    hipFuncSetAttribute(reinterpret_cast<const void*>(k2),
                        hipFuncAttributeMaxDynamicSharedMemorySize, 131072);
    hipFuncSetAttribute(reinterpret_cast<const void*>(attn_kernel),
                        hipFuncAttributeMaxDynamicSharedMemorySize, 65536);
    attr_done = true;
  }

  // fused fp32 -> bf16 converts (single launch; qkv_w rows permuted to grouped order)
  cvt_all<<<16384, 256, 0, stream>>>(qkv_w, out_w, ffn_w1, ffn_w2, src,
                                     wqkv, wout, wf1, wf2, srcb);

  // QKV projection + grouped head scatter (q scaled, v transposed): 8-phase 256^2
  gemm8p<2, 1><<<dim3(192, 1), 512, 131072, stream>>>(srcb, wqkv, qkv_b, nullptr,
                                                      qb_, kb_, vtb, 3072, 1024);
  // flash attention, 2-way KV-split, double-buffered staging -> O/l partials
  attn_kernel<<<512, 512, 65536, stream>>>(qb_, kb_, vtb, opart, lpart);
  // combine partials -> ctx [B,S,D] bf16
  attn_combine<<<4096, 256, 0, stream>>>(opart, lpart, ctxb);
  // output projection -> mha bf16 (split-1: no partial duplication; grid 256
  // blocks = 1/CU full coverage, 16 k-iters/block best amortization)
  gemm_bt<0, 1><<<dim3(32, 8, 1), 256, 0, stream>>>(ctxb, wout, out_b, mha,
                                                    nullptr, nullptr, nullptr, 4096, 1024, 1024);
  // LN1(src + mha) -> agg fp32 + bf16
  ln_kernel<1><<<4096, 256, 0, stream>>>(src, mha, ln1_g, ln1_b, aggf, aggb);
  // FFN1 + ReLU -> h bf16: 8-phase 256^2
  gemm8p<1, 1><<<dim3(256, 1), 512, 131072, stream>>>(aggb, wf1, ffn_b1, hb,
                                                      nullptr, nullptr, nullptr, 4096, 1024);
  // FFN2 -> ffn bf16 partials: 8-phase 256^2, split-K=4 (grid 64x4 = 256 blocks)
  gemm8p<0, 4><<<dim3(64, 4), 512, 131072, stream>>>(hb, wf2, ffn_b2, ffnf,
                                                     nullptr, nullptr, nullptr, 1024, 4096);
  // LN2(agg + sum ffn partials) -> d_out fp32
  ln_kernel<4><<<4096, 256, 0, stream>>>(aggf, ffnf, ln2_g, ln2_b, (float*)d_out, nullptr);
}